// Round 1
// baseline (2159.961 us; speedup 1.0000x reference)
//
#include <hip/hip_runtime.h>
#include <hip/hip_bf16.h>
#include <math.h>

// Problem constants (ConViT GPSA): B=16, N=576, D=1024, H=16, HD=64
#define B_ 16
#define N_ 576
#define D_ 1024
#define H_ 16
#define HD_ 64
#define BN_ (B_ * N_)   // 9216 rows

// ---------------------------------------------------------------------------
// Generic fp32 tiled GEMM: C[M,N] = A[M,K] @ Bm[K,N] (+ bias[N] if non-null)
// 64x64 tile, BK=16, 256 threads, 4x4 micro-tile per thread.
// M,N,K all divisible by tile sizes for this problem (9216/64, 2048/64, 1024/16).
// ---------------------------------------------------------------------------
__global__ __launch_bounds__(256) void gemm_f32(
    const float* __restrict__ A, const float* __restrict__ Bm,
    const float* __restrict__ bias, float* __restrict__ C,
    int M, int N, int K)
{
    __shared__ float As[16][68];   // As[k][row]  (transposed store, +4 pad)
    __shared__ float Bs[16][68];   // Bs[k][col]
    const int tid  = threadIdx.x;
    const int col0 = blockIdx.x * 64;
    const int row0 = blockIdx.y * 64;
    const int tx = tid & 15, ty = tid >> 4;
    const int ar = tid >> 2, ak = (tid & 3) << 2;    // A-load: row 0..63, k-offset
    const int bk = tid >> 4, bc = (tid & 15) << 2;   // B-load: k 0..15, col-offset
    const float* Ap = A  + (size_t)(row0 + ar) * K + ak;
    const float* Bp = Bm + (size_t)bk * N + col0 + bc;

    float acc[4][4] = {};
    for (int k0 = 0; k0 < K; k0 += 16) {
        float4 a4 = *(const float4*)(Ap + k0);
        float4 b4 = *(const float4*)(Bp + (size_t)k0 * N);
        __syncthreads();   // previous iteration's reads done
        As[ak + 0][ar] = a4.x; As[ak + 1][ar] = a4.y;
        As[ak + 2][ar] = a4.z; As[ak + 3][ar] = a4.w;
        *(float4*)&Bs[bk][bc] = b4;
        __syncthreads();
#pragma unroll
        for (int k = 0; k < 16; ++k) {
            float4 av = *(const float4*)&As[k][ty << 2];
            float4 bv = *(const float4*)&Bs[k][tx << 2];
            float aa[4] = {av.x, av.y, av.z, av.w};
            float bb[4] = {bv.x, bv.y, bv.z, bv.w};
#pragma unroll
            for (int i = 0; i < 4; ++i)
#pragma unroll
                for (int j = 0; j < 4; ++j)
                    acc[i][j] = fmaf(aa[i], bb[j], acc[i][j]);
        }
    }
    float4 bv4 = make_float4(0.f, 0.f, 0.f, 0.f);
    if (bias) bv4 = *(const float4*)&bias[col0 + (tx << 2)];
#pragma unroll
    for (int i = 0; i < 4; ++i) {
        int row = row0 + (ty << 2) + i;
        float4 o;
        o.x = acc[i][0] + bv4.x; o.y = acc[i][1] + bv4.y;
        o.z = acc[i][2] + bv4.z; o.w = acc[i][3] + bv4.w;
        *(float4*)(C + (size_t)row * N + col0 + (tx << 2)) = o;
    }
}

// ---------------------------------------------------------------------------
// pos_score[h,n,:] = softmax_m( rel[n,m,:] @ W_pos[:,h] + b_pos[h] )
// One wave (64 lanes) per (h,n) row; 576 = 64*9 columns per lane-strided loop.
// ---------------------------------------------------------------------------
__global__ __launch_bounds__(64) void pos_softmax(
    const float* __restrict__ rel, const float* __restrict__ W_pos,
    const float* __restrict__ b_pos, float* __restrict__ pos)
{
    const int h = blockIdx.x / N_;
    const int n = blockIdx.x % N_;
    const int lane = threadIdx.x;
    const float w0 = W_pos[h], w1 = W_pos[H_ + h], w2 = W_pos[2 * H_ + h];
    const float bb = b_pos[h];
    float vals[9];
    float mx = -INFINITY;
#pragma unroll
    for (int i = 0; i < 9; ++i) {
        int m = lane + (i << 6);
        const float* r = rel + ((size_t)n * N_ + m) * 3;
        float lg = fmaf(r[0], w0, fmaf(r[1], w1, fmaf(r[2], w2, bb)));
        vals[i] = lg;
        mx = fmaxf(mx, lg);
    }
#pragma unroll
    for (int off = 32; off; off >>= 1) mx = fmaxf(mx, __shfl_xor(mx, off, 64));
    float sum = 0.f;
#pragma unroll
    for (int i = 0; i < 9; ++i) { vals[i] = __expf(vals[i] - mx); sum += vals[i]; }
#pragma unroll
    for (int off = 32; off; off >>= 1) sum += __shfl_xor(sum, off, 64);
    const float inv = 1.f / sum;
    float* o = pos + ((size_t)h * N_ + n) * N_;
#pragma unroll
    for (int i = 0; i < 9; ++i) o[lane + (i << 6)] = vals[i] * inv;
}

// ---------------------------------------------------------------------------
// Attention per (b, h, 16-row tile):
//   S = (q_tile @ k^T) * scale ; softmax rows ; S = (1-g)*S + g*pos ; out = S @ v
// Renormalization attn/attn.sum is skipped: both mixed terms are softmaxes
// summing to 1, so the row sum is exactly (1-g)+g = 1.
// LDS: q 16x68 + kv 64x68 + S 16x584 = ~59 KB (<64 KB, allows 2 blocks/CU).
// ---------------------------------------------------------------------------
#define AROWS 16
#define MCH   64
#define SLD   (N_ + 8)   // 584 floats; 584*4 % 16 == 0 so float4 stays aligned

__global__ __launch_bounds__(256) void attn_kernel(
    const float* __restrict__ qk, const float* __restrict__ vbuf,
    const float* __restrict__ pos, const float* __restrict__ gating,
    float* __restrict__ ao)
{
    __shared__ float q_s[AROWS][68];
    __shared__ float kv_s[MCH][68];
    __shared__ float S[AROWS][SLD];

    const int bid = blockIdx.x;
    const int t  = bid % (N_ / AROWS);        // 0..35 row tile
    const int bh = bid / (N_ / AROWS);
    const int h  = bh % H_;
    const int b  = bh / H_;
    const int n0 = t * AROWS;
    const int tid = threadIdx.x;

    const float g   = 1.f / (1.f + __expf(-gating[h]));
    const float omg = 1.f - g;
    const float scale = 0.125f;               // HD^-0.5 = 1/8
    const size_t qkbase = (size_t)b * N_ * (2 * D_) + (size_t)h * HD_;

    // load q tile [16][64]: 256 float4 slots, one per thread
    {
        int r = tid >> 4, c4 = (tid & 15) << 2;
        *(float4*)&q_s[r][c4] =
            *(const float4*)&qk[qkbase + (size_t)(n0 + r) * (2 * D_) + c4];
    }

    // ---- scores: S[16][576] = q @ k^T * scale ----
    const int tn  = tid >> 4;          // row 0..15
    const int tm0 = (tid & 15) << 2;   // 4 consecutive m per thread
    for (int mc = 0; mc < N_; mc += MCH) {
        __syncthreads();
#pragma unroll
        for (int s = 0; s < 4; ++s) {
            int sl = tid + (s << 8);
            int rr = sl >> 4, c4 = (sl & 15) << 2;
            *(float4*)&kv_s[rr][c4] =
                *(const float4*)&qk[qkbase + D_ + (size_t)(mc + rr) * (2 * D_) + c4];
        }
        __syncthreads();
        float a0 = 0.f, a1 = 0.f, a2 = 0.f, a3 = 0.f;
#pragma unroll
        for (int d = 0; d < HD_; d += 4) {
            float4 q4 = *(const float4*)&q_s[tn][d];
            float4 k0 = *(const float4*)&kv_s[tm0 + 0][d];
            float4 k1 = *(const float4*)&kv_s[tm0 + 1][d];
            float4 k2 = *(const float4*)&kv_s[tm0 + 2][d];
            float4 k3 = *(const float4*)&kv_s[tm0 + 3][d];
            a0 += q4.x * k0.x + q4.y * k0.y + q4.z * k0.z + q4.w * k0.w;
            a1 += q4.x * k1.x + q4.y * k1.y + q4.z * k1.z + q4.w * k1.w;
            a2 += q4.x * k2.x + q4.y * k2.y + q4.z * k2.z + q4.w * k2.w;
            a3 += q4.x * k3.x + q4.y * k3.y + q4.z * k3.z + q4.w * k3.w;
        }
        *(float4*)&S[tn][mc + tm0] =
            make_float4(a0 * scale, a1 * scale, a2 * scale, a3 * scale);
    }
    __syncthreads();

    // ---- softmax over 576 + gated mix with pos ----
    {
        const int r = tid >> 4, j = tid & 15;   // 16 threads per row
        const float* prow = pos + ((size_t)h * N_ + n0 + r) * N_;
        float mx = -INFINITY;
#pragma unroll
        for (int i = 0; i < 36; ++i) mx = fmaxf(mx, S[r][j + (i << 4)]);
#pragma unroll
        for (int off = 8; off; off >>= 1) mx = fmaxf(mx, __shfl_xor(mx, off, 16));
        float sum = 0.f;
#pragma unroll
        for (int i = 0; i < 36; ++i) {
            int c = j + (i << 4);
            float e = __expf(S[r][c] - mx);
            S[r][c] = e;
            sum += e;
        }
#pragma unroll
        for (int off = 8; off; off >>= 1) sum += __shfl_xor(sum, off, 16);
        const float sc = omg / sum;
#pragma unroll
        for (int i = 0; i < 36; ++i) {
            int c = j + (i << 4);
            S[r][c] = fmaf(S[r][c], sc, g * prow[c]);
        }
    }

    // ---- out tile = S @ v  (16x576 @ 576x64) ----
    const int arr = tid >> 4;
    const int ac0 = (tid & 15) << 2;
    float acc[4] = {0.f, 0.f, 0.f, 0.f};
    const size_t vbase = (size_t)b * N_ * D_ + (size_t)h * HD_;
    for (int mc = 0; mc < N_; mc += MCH) {
        __syncthreads();
#pragma unroll
        for (int s = 0; s < 4; ++s) {
            int sl = tid + (s << 8);
            int rr = sl >> 4, c4 = (sl & 15) << 2;
            *(float4*)&kv_s[rr][c4] =
                *(const float4*)&vbuf[vbase + (size_t)(mc + rr) * D_ + c4];
        }
        __syncthreads();
#pragma unroll 8
        for (int m = 0; m < MCH; ++m) {
            float s = S[arr][mc + m];
            float4 v4 = *(const float4*)&kv_s[m][ac0];
            acc[0] = fmaf(s, v4.x, acc[0]);
            acc[1] = fmaf(s, v4.y, acc[1]);
            acc[2] = fmaf(s, v4.z, acc[2]);
            acc[3] = fmaf(s, v4.w, acc[3]);
        }
    }
    // write in [B, N, D] layout: out[b, n, h*64 + d]  (== transpose(0,2,1,3))
    *(float4*)&ao[((size_t)b * N_ + n0 + arr) * D_ + h * HD_ + ac0] =
        make_float4(acc[0], acc[1], acc[2], acc[3]);
}

// ---------------------------------------------------------------------------
extern "C" void kernel_launch(void* const* d_in, const int* in_sizes, int n_in,
                              void* d_out, int out_size, void* d_ws, size_t ws_size,
                              hipStream_t stream)
{
    const float* x      = (const float*)d_in[0];   // [B,N,D]
    const float* W_qk   = (const float*)d_in[1];   // [D,2D]
    const float* W_v    = (const float*)d_in[2];   // [D,D]
    const float* W_proj = (const float*)d_in[3];   // [D,D]
    const float* b_proj = (const float*)d_in[4];   // [D]
    const float* W_pos  = (const float*)d_in[5];   // [3,H]
    const float* b_pos  = (const float*)d_in[6];   // [H]
    const float* gating = (const float*)d_in[7];   // [H]
    const float* rel    = (const float*)d_in[8];   // [N,N,3]
    float* out = (float*)d_out;                    // [B,N,D]

    // workspace layout (fp32): qk | v | pos | ao  = ~172 MB total
    float* qk  = (float*)d_ws;                       // BN * 2048
    float* vb  = qk  + (size_t)BN_ * (2 * D_);       // BN * 1024
    float* pos = vb  + (size_t)BN_ * D_;             // H * N * N
    float* ao  = pos + (size_t)H_ * N_ * N_;         // BN * 1024

    // 1) qk = x @ W_qk
    gemm_f32<<<dim3((2 * D_) / 64, BN_ / 64), 256, 0, stream>>>(
        x, W_qk, nullptr, qk, BN_, 2 * D_, D_);
    // 2) v = x @ W_v
    gemm_f32<<<dim3(D_ / 64, BN_ / 64), 256, 0, stream>>>(
        x, W_v, nullptr, vb, BN_, D_, D_);
    // 3) positional softmax (batch-independent)
    pos_softmax<<<H_ * N_, 64, 0, stream>>>(rel, W_pos, b_pos, pos);
    // 4) gated attention
    attn_kernel<<<B_ * H_ * (N_ / AROWS), 256, 0, stream>>>(qk, vb, pos, gating, ao);
    // 5) out = ao @ W_proj + b_proj
    gemm_f32<<<dim3(D_ / 64, BN_ / 64), 256, 0, stream>>>(
        ao, W_proj, b_proj, out, BN_, D_, D_);
}

// Round 2
// 1369.883 us; speedup vs baseline: 1.5767x; 1.5767x over previous
//
#include <hip/hip_runtime.h>
#include <hip/hip_bf16.h>
#include <math.h>

// Problem constants (ConViT GPSA): B=16, N=576, D=1024, H=16, HD=64
#define B_ 16
#define N_ 576
#define D_ 1024
#define H_ 16
#define HD_ 64
#define BN_ (B_ * N_)   // 9216 rows

typedef __bf16 bf16x8 __attribute__((ext_vector_type(8)));
typedef __bf16 bf16x4 __attribute__((ext_vector_type(4)));
typedef float  f32x4  __attribute__((ext_vector_type(4)));

__device__ __forceinline__ float bf2f(unsigned short u) {
    union { unsigned int i; float f; } c; c.i = ((unsigned int)u) << 16; return c.f;
}

// ---------------------------------------------------------------------------
// cast fp32 -> bf16, 4 elems/thread (n must be divisible by 1024 per grid calc)
// ---------------------------------------------------------------------------
__global__ __launch_bounds__(256) void cast_bf16(
    const float* __restrict__ in, __bf16* __restrict__ out)
{
    size_t i = ((size_t)blockIdx.x * 256 + threadIdx.x) * 4;
    float4 v = *(const float4*)&in[i];
    bf16x4 o;
    o.x = (__bf16)v.x; o.y = (__bf16)v.y; o.z = (__bf16)v.z; o.w = (__bf16)v.w;
    *(bf16x4*)&out[i] = o;
}

// ---------------------------------------------------------------------------
// transpose + cast: W[K,N] fp32 -> Wt[N,K] bf16. 64x64 tiles, 256 threads.
// ---------------------------------------------------------------------------
__global__ __launch_bounds__(256) void transpose_cast(
    const float* __restrict__ W, __bf16* __restrict__ Wt, int K, int N)
{
    __shared__ float t[64][65];
    const int tid = threadIdx.x;
    const int k0 = blockIdx.y * 64, n0 = blockIdx.x * 64;
    const int r = tid >> 4, c4 = (tid & 15) << 2;
#pragma unroll
    for (int s = 0; s < 4; ++s) {
        int rr = r + (s << 4);
        float4 w = *(const float4*)&W[(size_t)(k0 + rr) * N + n0 + c4];
        t[rr][c4] = w.x; t[rr][c4 + 1] = w.y; t[rr][c4 + 2] = w.z; t[rr][c4 + 3] = w.w;
    }
    __syncthreads();
#pragma unroll
    for (int s = 0; s < 4; ++s) {
        int rr = r + (s << 4);          // local n index
        bf16x4 o;
        o.x = (__bf16)t[c4 + 0][rr]; o.y = (__bf16)t[c4 + 1][rr];
        o.z = (__bf16)t[c4 + 2][rr]; o.w = (__bf16)t[c4 + 3][rr];
        *(bf16x4*)&Wt[(size_t)(n0 + rr) * K + k0 + c4] = o;
    }
}

// ---------------------------------------------------------------------------
// bf16 MFMA GEMM (m97 structure): C[M,N] = A[M,K] @ Bt[N,K]^T (+bias)
// 128x128 tile, BK=32, 256 threads = 4 waves (2x2), each wave 64x64 via
// 4x4 grid of 16x16x32 MFMA. Staging via global_load_lds width 16 with
// XOR k-chunk swizzle (chunk ^= (row>>1)&3) so frag ds_read_b128 is 2-way max.
// ---------------------------------------------------------------------------
template<int BF16OUT>
__global__ __launch_bounds__(256) void gemm_mfma(
    const __bf16* __restrict__ A, const __bf16* __restrict__ Bt,
    const float* __restrict__ bias, void* __restrict__ Cp,
    int M, int N, int K)
{
    __shared__ __bf16 As[128 * 32];
    __shared__ __bf16 Bs[128 * 32];
    const int tid  = threadIdx.x;
    const int lane = tid & 63;
    const int wave = tid >> 6;
    const int m0 = blockIdx.y * 128;
    const int n0 = blockIdx.x * 128;
    const int wm = (wave >> 1) * 64;
    const int wn = (wave & 1) * 64;

    // staging: 16B chunk c = tid + s*256; row r=c>>2, pos q=c&3, src chunk q^((r>>1)&3)
    const int r0 = tid >> 2, q0 = tid & 3;
    const int qs0 = q0 ^ ((r0 >> 1) & 3);
    const int r1 = r0 + 64;
    const int qs1 = q0 ^ ((r1 >> 1) & 3);
    const __bf16* srcA0 = A  + (size_t)(m0 + r0) * K + qs0 * 8;
    const __bf16* srcA1 = A  + (size_t)(m0 + r1) * K + qs1 * 8;
    const __bf16* srcB0 = Bt + (size_t)(n0 + r0) * K + qs0 * 8;
    const __bf16* srcB1 = Bt + (size_t)(n0 + r1) * K + qs1 * 8;
    __bf16* dstA0 = &As[(wave * 64) * 8];          // wave-uniform base; HW adds lane*16
    __bf16* dstA1 = &As[(256 + wave * 64) * 8];
    __bf16* dstB0 = &Bs[(wave * 64) * 8];
    __bf16* dstB1 = &Bs[(256 + wave * 64) * 8];

    // fragment LDS offsets (in bf16 elements)
    const int fr = lane & 15, quad = lane >> 4;
    int aoff[4], boff[4];
#pragma unroll
    for (int i = 0; i < 4; ++i) {
        int row = wm + i * 16 + fr;
        aoff[i] = row * 32 + (quad ^ ((row >> 1) & 3)) * 8;
    }
#pragma unroll
    for (int j = 0; j < 4; ++j) {
        int row = wn + j * 16 + fr;
        boff[j] = row * 32 + (quad ^ ((row >> 1) & 3)) * 8;
    }

    f32x4 acc[4][4];
#pragma unroll
    for (int i = 0; i < 4; ++i)
#pragma unroll
        for (int j = 0; j < 4; ++j)
            acc[i][j] = (f32x4){0.f, 0.f, 0.f, 0.f};

    for (int k0 = 0; k0 < K; k0 += 32) {
        __syncthreads();
        __builtin_amdgcn_global_load_lds(
            (const __attribute__((address_space(1))) void*)(srcA0 + k0),
            (__attribute__((address_space(3))) void*)dstA0, 16, 0, 0);
        __builtin_amdgcn_global_load_lds(
            (const __attribute__((address_space(1))) void*)(srcA1 + k0),
            (__attribute__((address_space(3))) void*)dstA1, 16, 0, 0);
        __builtin_amdgcn_global_load_lds(
            (const __attribute__((address_space(1))) void*)(srcB0 + k0),
            (__attribute__((address_space(3))) void*)dstB0, 16, 0, 0);
        __builtin_amdgcn_global_load_lds(
            (const __attribute__((address_space(1))) void*)(srcB1 + k0),
            (__attribute__((address_space(3))) void*)dstB1, 16, 0, 0);
        __syncthreads();   // drains vmcnt(0): staging complete

        bf16x8 af[4], bfv[4];
#pragma unroll
        for (int i = 0; i < 4; ++i) af[i]  = *(const bf16x8*)&As[aoff[i]];
#pragma unroll
        for (int j = 0; j < 4; ++j) bfv[j] = *(const bf16x8*)&Bs[boff[j]];
#pragma unroll
        for (int i = 0; i < 4; ++i)
#pragma unroll
            for (int j = 0; j < 4; ++j)
                acc[i][j] = __builtin_amdgcn_mfma_f32_16x16x32_bf16(
                    af[i], bfv[j], acc[i][j], 0, 0, 0);
    }

    // epilogue: C/D layout col=lane&15, row=quad*4+reg  [verified m89/m91]
    const int colb = n0 + wn + fr;
    const int rowb = m0 + wm + quad * 4;
#pragma unroll
    for (int j = 0; j < 4; ++j) {
        int col = colb + j * 16;
        float bv = bias ? bias[col] : 0.0f;
#pragma unroll
        for (int i = 0; i < 4; ++i) {
            int row = rowb + i * 16;
#pragma unroll
            for (int t = 0; t < 4; ++t) {
                float v = acc[i][j][t] + bv;
                if (BF16OUT) ((__bf16*)Cp)[(size_t)(row + t) * N + col] = (__bf16)v;
                else         ((float*)Cp)[(size_t)(row + t) * N + col] = v;
            }
        }
    }
}

// ---------------------------------------------------------------------------
// pos_score[h,n,:] = softmax_m( rel[n,m,:] @ W_pos[:,h] + b_pos[h] )  (fp32)
// ---------------------------------------------------------------------------
__global__ __launch_bounds__(64) void pos_softmax(
    const float* __restrict__ rel, const float* __restrict__ W_pos,
    const float* __restrict__ b_pos, float* __restrict__ pos)
{
    const int h = blockIdx.x / N_;
    const int n = blockIdx.x % N_;
    const int lane = threadIdx.x;
    const float w0 = W_pos[h], w1 = W_pos[H_ + h], w2 = W_pos[2 * H_ + h];
    const float bb = b_pos[h];
    float vals[9];
    float mx = -INFINITY;
#pragma unroll
    for (int i = 0; i < 9; ++i) {
        int m = lane + (i << 6);
        const float* r = rel + ((size_t)n * N_ + m) * 3;
        float lg = fmaf(r[0], w0, fmaf(r[1], w1, fmaf(r[2], w2, bb)));
        vals[i] = lg;
        mx = fmaxf(mx, lg);
    }
#pragma unroll
    for (int off = 32; off; off >>= 1) mx = fmaxf(mx, __shfl_xor(mx, off, 64));
    float sum = 0.f;
#pragma unroll
    for (int i = 0; i < 9; ++i) { vals[i] = __expf(vals[i] - mx); sum += vals[i]; }
#pragma unroll
    for (int off = 32; off; off >>= 1) sum += __shfl_xor(sum, off, 64);
    const float inv = 1.f / sum;
    float* o = pos + ((size_t)h * N_ + n) * N_;
#pragma unroll
    for (int i = 0; i < 9; ++i) o[lane + (i << 6)] = vals[i] * inv;
}

// ---------------------------------------------------------------------------
// Gated attention per (b, h, 16-row tile). qk/v are bf16; pos fp32; out bf16.
// Renormalization skipped: both mixed terms are softmaxes (row sum == 1).
// Bank-conflict fix vs R1: thread's 4 m-columns are strided (j + 16u), so
// kv_s row reads start at bank 4j mod 32 -> 2-way max (free, m136).
// ---------------------------------------------------------------------------
#define AROWS 16

__global__ __launch_bounds__(256) void attn_kernel(
    const ushort* __restrict__ qk, const ushort* __restrict__ vbuf,
    const float* __restrict__ pos, const float* __restrict__ gating,
    __bf16* __restrict__ ao)
{
    __shared__ float q_s[AROWS][68];
    __shared__ float kv_s[64][68];
    __shared__ float S[AROWS][584];

    const int bid = blockIdx.x;
    const int t  = bid % (N_ / AROWS);
    const int bh = bid / (N_ / AROWS);
    const int h  = bh % H_;
    const int b  = bh / H_;
    const int n0 = t * AROWS;
    const int tid = threadIdx.x;

    const float g   = 1.f / (1.f + __expf(-gating[h]));
    const float omg = 1.f - g;
    const float scale = 0.125f;
    const size_t qkbase = (size_t)b * N_ * (2 * D_) + (size_t)h * HD_;

    // q tile [16][64]
    {
        int r = tid >> 4, c4 = (tid & 15) << 2;
        ushort4 u = *(const ushort4*)&qk[qkbase + (size_t)(n0 + r) * (2 * D_) + c4];
        q_s[r][c4] = bf2f(u.x); q_s[r][c4 + 1] = bf2f(u.y);
        q_s[r][c4 + 2] = bf2f(u.z); q_s[r][c4 + 3] = bf2f(u.w);
    }

    // ---- scores ----
    const int tn = tid >> 4;
    const int tj = tid & 15;
    for (int mc = 0; mc < N_; mc += 64) {
        __syncthreads();
#pragma unroll
        for (int s = 0; s < 4; ++s) {
            int sl = tid + (s << 8);
            int rr = sl >> 4, c4 = (sl & 15) << 2;
            ushort4 u = *(const ushort4*)&qk[qkbase + D_ + (size_t)(mc + rr) * (2 * D_) + c4];
            kv_s[rr][c4] = bf2f(u.x); kv_s[rr][c4 + 1] = bf2f(u.y);
            kv_s[rr][c4 + 2] = bf2f(u.z); kv_s[rr][c4 + 3] = bf2f(u.w);
        }
        __syncthreads();
        float a0 = 0.f, a1 = 0.f, a2 = 0.f, a3 = 0.f;
#pragma unroll
        for (int d = 0; d < HD_; d += 4) {
            float4 q4 = *(const float4*)&q_s[tn][d];
            float4 k0 = *(const float4*)&kv_s[tj][d];
            float4 k1 = *(const float4*)&kv_s[tj + 16][d];
            float4 k2 = *(const float4*)&kv_s[tj + 32][d];
            float4 k3 = *(const float4*)&kv_s[tj + 48][d];
            a0 += q4.x * k0.x + q4.y * k0.y + q4.z * k0.z + q4.w * k0.w;
            a1 += q4.x * k1.x + q4.y * k1.y + q4.z * k1.z + q4.w * k1.w;
            a2 += q4.x * k2.x + q4.y * k2.y + q4.z * k2.z + q4.w * k2.w;
            a3 += q4.x * k3.x + q4.y * k3.y + q4.z * k3.z + q4.w * k3.w;
        }
        S[tn][mc + tj]      = a0 * scale;
        S[tn][mc + tj + 16] = a1 * scale;
        S[tn][mc + tj + 32] = a2 * scale;
        S[tn][mc + tj + 48] = a3 * scale;
    }
    __syncthreads();

    // ---- softmax + gated mix ----
    {
        const int r = tid >> 4, j = tid & 15;
        const float* prow = pos + ((size_t)h * N_ + n0 + r) * N_;
        float mx = -INFINITY;
#pragma unroll
        for (int i = 0; i < 36; ++i) mx = fmaxf(mx, S[r][j + (i << 4)]);
#pragma unroll
        for (int off = 8; off; off >>= 1) mx = fmaxf(mx, __shfl_xor(mx, off, 16));
        float sum = 0.f;
#pragma unroll
        for (int i = 0; i < 36; ++i) {
            int c = j + (i << 4);
            float e = __expf(S[r][c] - mx);
            S[r][c] = e;
            sum += e;
        }
#pragma unroll
        for (int off = 8; off; off >>= 1) sum += __shfl_xor(sum, off, 16);
        const float sc = omg / sum;
#pragma unroll
        for (int i = 0; i < 36; ++i) {
            int c = j + (i << 4);
            S[r][c] = fmaf(S[r][c], sc, g * prow[c]);
        }
    }

    // ---- out tile = S @ v ----
    const int arr = tid >> 4;
    const int ac0 = (tid & 15) << 2;
    float acc[4] = {0.f, 0.f, 0.f, 0.f};
    const size_t vbase = (size_t)b * N_ * D_ + (size_t)h * HD_;
    for (int mc = 0; mc < N_; mc += 64) {
        __syncthreads();
#pragma unroll
        for (int s = 0; s < 4; ++s) {
            int sl = tid + (s << 8);
            int rr = sl >> 4, c4 = (sl & 15) << 2;
            ushort4 u = *(const ushort4*)&vbuf[vbase + (size_t)(mc + rr) * D_ + c4];
            kv_s[rr][c4] = bf2f(u.x); kv_s[rr][c4 + 1] = bf2f(u.y);
            kv_s[rr][c4 + 2] = bf2f(u.z); kv_s[rr][c4 + 3] = bf2f(u.w);
        }
        __syncthreads();
#pragma unroll 8
        for (int m = 0; m < 64; ++m) {
            float s = S[arr][mc + m];
            float4 v4 = *(const float4*)&kv_s[m][ac0];
            acc[0] = fmaf(s, v4.x, acc[0]);
            acc[1] = fmaf(s, v4.y, acc[1]);
            acc[2] = fmaf(s, v4.z, acc[2]);
            acc[3] = fmaf(s, v4.w, acc[3]);
        }
    }
    bf16x4 o;
    o.x = (__bf16)acc[0]; o.y = (__bf16)acc[1];
    o.z = (__bf16)acc[2]; o.w = (__bf16)acc[3];
    *(bf16x4*)&ao[((size_t)b * N_ + n0 + arr) * D_ + h * HD_ + ac0] = o;
}

// ---------------------------------------------------------------------------
extern "C" void kernel_launch(void* const* d_in, const int* in_sizes, int n_in,
                              void* d_out, int out_size, void* d_ws, size_t ws_size,
                              hipStream_t stream)
{
    const float* x      = (const float*)d_in[0];
    const float* W_qk   = (const float*)d_in[1];
    const float* W_v    = (const float*)d_in[2];
    const float* W_proj = (const float*)d_in[3];
    const float* b_proj = (const float*)d_in[4];
    const float* W_pos  = (const float*)d_in[5];
    const float* b_pos  = (const float*)d_in[6];
    const float* gating = (const float*)d_in[7];
    const float* rel    = (const float*)d_in[8];
    float* out = (float*)d_out;

    // workspace carve (bytes; all sizes 16B-aligned). Total ~124 MB.
    char* p = (char*)d_ws;
    __bf16* xb   = (__bf16*)p;  p += (size_t)BN_ * D_ * 2;          // 18.9 MB
    __bf16* wqkt = (__bf16*)p;  p += (size_t)(2 * D_) * D_ * 2;     //  4.2 MB
    __bf16* wvt  = (__bf16*)p;  p += (size_t)D_ * D_ * 2;           //  2.1 MB
    __bf16* wpt  = (__bf16*)p;  p += (size_t)D_ * D_ * 2;           //  2.1 MB
    __bf16* qkb  = (__bf16*)p;  p += (size_t)BN_ * (2 * D_) * 2;    // 37.7 MB
    __bf16* vbb  = (__bf16*)p;  p += (size_t)BN_ * D_ * 2;          // 18.9 MB
    __bf16* aob  = (__bf16*)p;  p += (size_t)BN_ * D_ * 2;          // 18.9 MB
    float*  pos  = (float*)p;                                       // 21.2 MB

    // casts / transposes
    cast_bf16<<<(BN_ * D_) / 1024, 256, 0, stream>>>(x, xb);
    transpose_cast<<<dim3((2 * D_) / 64, D_ / 64), 256, 0, stream>>>(W_qk, wqkt, D_, 2 * D_);
    transpose_cast<<<dim3(D_ / 64, D_ / 64), 256, 0, stream>>>(W_v, wvt, D_, D_);
    transpose_cast<<<dim3(D_ / 64, D_ / 64), 256, 0, stream>>>(W_proj, wpt, D_, D_);

    // qk = x @ W_qk  (bf16 out)
    gemm_mfma<1><<<dim3((2 * D_) / 128, BN_ / 128), 256, 0, stream>>>(
        xb, wqkt, nullptr, qkb, BN_, 2 * D_, D_);
    // v = x @ W_v  (bf16 out)
    gemm_mfma<1><<<dim3(D_ / 128, BN_ / 128), 256, 0, stream>>>(
        xb, wvt, nullptr, vbb, BN_, D_, D_);
    // positional softmax
    pos_softmax<<<H_ * N_, 64, 0, stream>>>(rel, W_pos, b_pos, pos);
    // gated attention (bf16 in/out)
    attn_kernel<<<B_ * H_ * (N_ / AROWS), 256, 0, stream>>>(
        (const ushort*)qkb, (const ushort*)vbb, pos, gating, aob);
    // out = ao @ W_proj + b_proj  (fp32 out)
    gemm_mfma<0><<<dim3(D_ / 128, BN_ / 128), 256, 0, stream>>>(
        aob, wpt, b_proj, out, BN_, D_, D_);
}

// Round 3
// 707.182 us; speedup vs baseline: 3.0543x; 1.9371x over previous
//
#include <hip/hip_runtime.h>
#include <hip/hip_bf16.h>
#include <math.h>

// Problem constants (ConViT GPSA): B=16, N=576, D=1024, H=16, HD=64
#define B_ 16
#define N_ 576
#define D_ 1024
#define H_ 16
#define HD_ 64
#define BN_ (B_ * N_)   // 9216 rows

typedef __bf16 bf16x8 __attribute__((ext_vector_type(8)));
typedef __bf16 bf16x4 __attribute__((ext_vector_type(4)));
typedef float  f32x4  __attribute__((ext_vector_type(4)));

// ---------------------------------------------------------------------------
// cast fp32 -> bf16, 4 elems/thread
// ---------------------------------------------------------------------------
__global__ __launch_bounds__(256) void cast_bf16(
    const float* __restrict__ in, __bf16* __restrict__ out)
{
    size_t i = ((size_t)blockIdx.x * 256 + threadIdx.x) * 4;
    float4 v = *(const float4*)&in[i];
    bf16x4 o;
    o.x = (__bf16)v.x; o.y = (__bf16)v.y; o.z = (__bf16)v.z; o.w = (__bf16)v.w;
    *(bf16x4*)&out[i] = o;
}

// ---------------------------------------------------------------------------
// transpose + cast: W[K,N] fp32 -> Wt[N,K] bf16. 64x64 tiles, 256 threads.
// ---------------------------------------------------------------------------
__global__ __launch_bounds__(256) void transpose_cast(
    const float* __restrict__ W, __bf16* __restrict__ Wt, int K, int N)
{
    __shared__ float t[64][65];
    const int tid = threadIdx.x;
    const int k0 = blockIdx.y * 64, n0 = blockIdx.x * 64;
    const int r = tid >> 4, c4 = (tid & 15) << 2;
#pragma unroll
    for (int s = 0; s < 4; ++s) {
        int rr = r + (s << 4);
        float4 w = *(const float4*)&W[(size_t)(k0 + rr) * N + n0 + c4];
        t[rr][c4] = w.x; t[rr][c4 + 1] = w.y; t[rr][c4 + 2] = w.z; t[rr][c4 + 3] = w.w;
    }
    __syncthreads();
#pragma unroll
    for (int s = 0; s < 4; ++s) {
        int rr = r + (s << 4);          // local n index
        bf16x4 o;
        o.x = (__bf16)t[c4 + 0][rr]; o.y = (__bf16)t[c4 + 1][rr];
        o.z = (__bf16)t[c4 + 2][rr]; o.w = (__bf16)t[c4 + 3][rr];
        *(bf16x4*)&Wt[(size_t)(n0 + rr) * K + k0 + c4] = o;
    }
}

// ---------------------------------------------------------------------------
// bf16 MFMA GEMM (m97 structure): C[M,N] = A[M,K] @ Bt[N,K]^T (+bias)
// OUTMODE: 0 = fp32 C[M,N]; 1 = bf16 C[M,N];
//          2 = bf16 V^T: vt[((row/576)*1024 + col)*576 + row%576]  (N must be 1024)
// ---------------------------------------------------------------------------
template<int OUTMODE>
__global__ __launch_bounds__(256) void gemm_mfma(
    const __bf16* __restrict__ A, const __bf16* __restrict__ Bt,
    const float* __restrict__ bias, void* __restrict__ Cp,
    int M, int N, int K)
{
    __shared__ __bf16 As[128 * 32];
    __shared__ __bf16 Bs[128 * 32];
    const int tid  = threadIdx.x;
    const int lane = tid & 63;
    const int wave = tid >> 6;
    const int m0 = blockIdx.y * 128;
    const int n0 = blockIdx.x * 128;
    const int wm = (wave >> 1) * 64;
    const int wn = (wave & 1) * 64;

    const int r0 = tid >> 2, q0 = tid & 3;
    const int qs0 = q0 ^ ((r0 >> 1) & 3);
    const int r1 = r0 + 64;
    const int qs1 = q0 ^ ((r1 >> 1) & 3);
    const __bf16* srcA0 = A  + (size_t)(m0 + r0) * K + qs0 * 8;
    const __bf16* srcA1 = A  + (size_t)(m0 + r1) * K + qs1 * 8;
    const __bf16* srcB0 = Bt + (size_t)(n0 + r0) * K + qs0 * 8;
    const __bf16* srcB1 = Bt + (size_t)(n0 + r1) * K + qs1 * 8;
    __bf16* dstA0 = &As[(wave * 64) * 8];
    __bf16* dstA1 = &As[(256 + wave * 64) * 8];
    __bf16* dstB0 = &Bs[(wave * 64) * 8];
    __bf16* dstB1 = &Bs[(256 + wave * 64) * 8];

    const int fr = lane & 15, quad = lane >> 4;
    int aoff[4], boff[4];
#pragma unroll
    for (int i = 0; i < 4; ++i) {
        int row = wm + i * 16 + fr;
        aoff[i] = row * 32 + (quad ^ ((row >> 1) & 3)) * 8;
    }
#pragma unroll
    for (int j = 0; j < 4; ++j) {
        int row = wn + j * 16 + fr;
        boff[j] = row * 32 + (quad ^ ((row >> 1) & 3)) * 8;
    }

    f32x4 acc[4][4];
#pragma unroll
    for (int i = 0; i < 4; ++i)
#pragma unroll
        for (int j = 0; j < 4; ++j)
            acc[i][j] = (f32x4){0.f, 0.f, 0.f, 0.f};

    for (int k0 = 0; k0 < K; k0 += 32) {
        __syncthreads();
        __builtin_amdgcn_global_load_lds(
            (const __attribute__((address_space(1))) void*)(srcA0 + k0),
            (__attribute__((address_space(3))) void*)dstA0, 16, 0, 0);
        __builtin_amdgcn_global_load_lds(
            (const __attribute__((address_space(1))) void*)(srcA1 + k0),
            (__attribute__((address_space(3))) void*)dstA1, 16, 0, 0);
        __builtin_amdgcn_global_load_lds(
            (const __attribute__((address_space(1))) void*)(srcB0 + k0),
            (__attribute__((address_space(3))) void*)dstB0, 16, 0, 0);
        __builtin_amdgcn_global_load_lds(
            (const __attribute__((address_space(1))) void*)(srcB1 + k0),
            (__attribute__((address_space(3))) void*)dstB1, 16, 0, 0);
        __syncthreads();

        bf16x8 af[4], bfv[4];
#pragma unroll
        for (int i = 0; i < 4; ++i) af[i]  = *(const bf16x8*)&As[aoff[i]];
#pragma unroll
        for (int j = 0; j < 4; ++j) bfv[j] = *(const bf16x8*)&Bs[boff[j]];
#pragma unroll
        for (int i = 0; i < 4; ++i)
#pragma unroll
            for (int j = 0; j < 4; ++j)
                acc[i][j] = __builtin_amdgcn_mfma_f32_16x16x32_bf16(
                    af[i], bfv[j], acc[i][j], 0, 0, 0);
    }

    // epilogue: C/D layout col=lane&15, row=quad*4+reg  [verified m89/m91]
    const int colb = n0 + wn + fr;
    const int rowb = m0 + wm + quad * 4;
#pragma unroll
    for (int j = 0; j < 4; ++j) {
        int col = colb + j * 16;
        float bv = (OUTMODE == 0 && bias) ? bias[col] : 0.0f;
#pragma unroll
        for (int i = 0; i < 4; ++i) {
            if (OUTMODE == 2) {
                int rowa = rowb + i * 16;
                int bb = rowa / 576;           // batch
                int ml = rowa - bb * 576;      // m within batch (ml%4==0, never crosses)
                bf16x4 o4;
#pragma unroll
                for (int t = 0; t < 4; ++t) o4[t] = (__bf16)acc[i][j][t];
                *(bf16x4*)&((__bf16*)Cp)[((size_t)bb * 1024 + col) * 576 + ml] = o4;
            } else {
                int row = rowb + i * 16;
#pragma unroll
                for (int t = 0; t < 4; ++t) {
                    float v = acc[i][j][t] + bv;
                    if (OUTMODE == 1) ((__bf16*)Cp)[(size_t)(row + t) * N + col] = (__bf16)v;
                    else              ((float*)Cp)[(size_t)(row + t) * N + col] = v;
                }
            }
        }
    }
}

// ---------------------------------------------------------------------------
// pos_score[h,n,:] = softmax_m( rel[n,m,:] @ W_pos[:,h] + b_pos[h] )  (fp32)
// ---------------------------------------------------------------------------
__global__ __launch_bounds__(64) void pos_softmax(
    const float* __restrict__ rel, const float* __restrict__ W_pos,
    const float* __restrict__ b_pos, float* __restrict__ pos)
{
    const int h = blockIdx.x / N_;
    const int n = blockIdx.x % N_;
    const int lane = threadIdx.x;
    const float w0 = W_pos[h], w1 = W_pos[H_ + h], w2 = W_pos[2 * H_ + h];
    const float bb = b_pos[h];
    float vals[9];
    float mx = -INFINITY;
#pragma unroll
    for (int i = 0; i < 9; ++i) {
        int m = lane + (i << 6);
        const float* r = rel + ((size_t)n * N_ + m) * 3;
        float lg = fmaf(r[0], w0, fmaf(r[1], w1, fmaf(r[2], w2, bb)));
        vals[i] = lg;
        mx = fmaxf(mx, lg);
    }
#pragma unroll
    for (int off = 32; off; off >>= 1) mx = fmaxf(mx, __shfl_xor(mx, off, 64));
    float sum = 0.f;
#pragma unroll
    for (int i = 0; i < 9; ++i) { vals[i] = __expf(vals[i] - mx); sum += vals[i]; }
#pragma unroll
    for (int off = 32; off; off >>= 1) sum += __shfl_xor(sum, off, 64);
    const float inv = 1.f / sum;
    float* o = pos + ((size_t)h * N_ + n) * N_;
#pragma unroll
    for (int i = 0; i < 9; ++i) o[lane + (i << 6)] = vals[i] * inv;
}

// ---------------------------------------------------------------------------
// MFMA gated attention. Block = (b, h, 64 q-rows), 4 waves, wave = 16 q-rows.
// Wave-private throughout -> NO __syncthreads.
//   S[16x576] in registers via MFMA (Q,K frags direct from global, L2-served)
//   in-register softmax (C-layout rows=quad*4+reg, 16-lane butterflies)
//   P = (1-g)*softmax + g*pos  -> wave-private LDS tile [n=16][m=584]
//   O^T = V^T @ P^T via MFMA (A-frags from vt global, B-frags = P rows in LDS)
//   repack O via LDS -> coalesced 16B stores. Renorm skipped (row sum == 1).
// ---------------------------------------------------------------------------
#define PLD 584   // P leading dim in bf16 (16B-aligned rows; word-stride%32==4 -> 2-way max)

__global__ __launch_bounds__(256, 2) void attn_mfma(
    const __bf16* __restrict__ qk, const __bf16* __restrict__ vt,
    const float* __restrict__ pos, const float* __restrict__ gating,
    __bf16* __restrict__ ao)
{
    __shared__ __bf16 Psm[4][16][PLD];   // 74,752 B -> 2 blocks/CU

    const int bid = blockIdx.x;
    const int qt = bid % 9;
    const int bh = bid / 9;
    const int h  = bh & (H_ - 1);
    const int b  = bh >> 4;
    const int tid  = threadIdx.x;
    const int lane = tid & 63, wave = tid >> 6;
    const int fr = lane & 15, quad = lane >> 4;
    const int n0 = qt * 64 + wave * 16;       // wave's first q row

    const float g   = 1.f / (1.f + __expf(-gating[h]));
    const float omg = 1.f - g;
    const float scale = 0.125f;               // HD^-0.5

    const size_t qbase = (size_t)b * N_ * (2 * D_) + h * HD_;
    const size_t kbase = qbase + D_;

    // Q A-frags: A[m=fr][k=quad*8+j], K=64 -> 2 k-blocks
    const __bf16* qp = &qk[qbase + (size_t)(n0 + fr) * (2 * D_) + quad * 8];
    bf16x8 qf0 = *(const bf16x8*)qp;
    bf16x8 qf1 = *(const bf16x8*)(qp + 32);

    // ---- S = Q @ K^T : 36 col-tiles of 16, each 2 MFMA ----
    f32x4 S[36];
#pragma unroll 4
    for (int ct = 0; ct < 36; ++ct) {
        const __bf16* kp = &qk[kbase + (size_t)(ct * 16 + fr) * (2 * D_) + quad * 8];
        bf16x8 k0 = *(const bf16x8*)kp;
        bf16x8 k1 = *(const bf16x8*)(kp + 32);
        f32x4 a = (f32x4){0.f, 0.f, 0.f, 0.f};
        a = __builtin_amdgcn_mfma_f32_16x16x32_bf16(qf0, k0, a, 0, 0, 0);
        a = __builtin_amdgcn_mfma_f32_16x16x32_bf16(qf1, k1, a, 0, 0, 0);
        S[ct] = a;
    }

    // ---- softmax rows (row = quad*4+t, cols = ct*16+fr) ----
    float mxv[4], inv[4];
#pragma unroll
    for (int t = 0; t < 4; ++t) {
        float m = -1e30f;
#pragma unroll
        for (int ct = 0; ct < 36; ++ct) m = fmaxf(m, S[ct][t]);
        m = fmaxf(m, __shfl_xor(m, 1, 16));
        m = fmaxf(m, __shfl_xor(m, 2, 16));
        m = fmaxf(m, __shfl_xor(m, 4, 16));
        m = fmaxf(m, __shfl_xor(m, 8, 16));
        mxv[t] = m;
    }
#pragma unroll
    for (int t = 0; t < 4; ++t) {
        float s = 0.f;
#pragma unroll
        for (int ct = 0; ct < 36; ++ct) {
            float e = __expf(scale * (S[ct][t] - mxv[t]));
            S[ct][t] = e;
            s += e;
        }
        s += __shfl_xor(s, 1, 16);
        s += __shfl_xor(s, 2, 16);
        s += __shfl_xor(s, 4, 16);
        s += __shfl_xor(s, 8, 16);
        inv[t] = omg / s;
    }

    // ---- P = e*inv + g*pos -> LDS (wave-private) ----
    const size_t posbase = ((size_t)h * N_ + n0 + quad * 4) * N_;
#pragma unroll 4
    for (int ct = 0; ct < 36; ++ct) {
        int col = ct * 16 + fr;
#pragma unroll
        for (int t = 0; t < 4; ++t) {
            float p = fmaf(S[ct][t], inv[t], g * pos[posbase + (size_t)t * N_ + col]);
            Psm[wave][quad * 4 + t][col] = (__bf16)p;
        }
    }

    // ---- O^T[64d x 16n] = V^T @ P^T : A = vt rows (d), Bt = P rows (n) ----
    f32x4 O[4];
#pragma unroll
    for (int dt = 0; dt < 4; ++dt) O[dt] = (f32x4){0.f, 0.f, 0.f, 0.f};
    const size_t vtb = (size_t)bh * HD_ * N_;
#pragma unroll 3
    for (int kb = 0; kb < 18; ++kb) {
        bf16x8 pf = *(const bf16x8*)&Psm[wave][fr][kb * 32 + quad * 8];
#pragma unroll
        for (int dt = 0; dt < 4; ++dt) {
            bf16x8 vf = *(const bf16x8*)&vt[vtb + (size_t)(dt * 16 + fr) * N_ + kb * 32 + quad * 8];
            O[dt] = __builtin_amdgcn_mfma_f32_16x16x32_bf16(vf, pf, O[dt], 0, 0, 0);
        }
    }

    // ---- repack O via wave-private LDS (reuse Psm region), coalesced store ----
    asm volatile("s_waitcnt lgkmcnt(0)");    // all P reads done before overwrite
    __bf16* Osm = &Psm[wave][0][0];          // layout [n=16][d=64]
#pragma unroll
    for (int dt = 0; dt < 4; ++dt) {
        bf16x4 o4;
#pragma unroll
        for (int t = 0; t < 4; ++t) o4[t] = (__bf16)O[dt][t];
        // lane holds O^T[d = dt*16+quad*4+t][n = fr]
        *(bf16x4*)&Osm[fr * 64 + dt * 16 + quad * 4] = o4;
    }
    asm volatile("s_waitcnt lgkmcnt(0)");    // Osm writes visible to own-wave reads
#pragma unroll
    for (int s = 0; s < 2; ++s) {
        int c   = lane + s * 64;             // 0..127 chunks of 16B
        int row = c >> 3;                    // n row 0..15
        int off = (c & 7) * 8;               // d offset
        bf16x8 ov = *(const bf16x8*)&Osm[row * 64 + off];
        *(bf16x8*)&ao[((size_t)b * N_ + n0 + row) * D_ + h * HD_ + off] = ov;
    }
}

// ---------------------------------------------------------------------------
extern "C" void kernel_launch(void* const* d_in, const int* in_sizes, int n_in,
                              void* d_out, int out_size, void* d_ws, size_t ws_size,
                              hipStream_t stream)
{
    const float* x      = (const float*)d_in[0];
    const float* W_qk   = (const float*)d_in[1];
    const float* W_v    = (const float*)d_in[2];
    const float* W_proj = (const float*)d_in[3];
    const float* b_proj = (const float*)d_in[4];
    const float* W_pos  = (const float*)d_in[5];
    const float* b_pos  = (const float*)d_in[6];
    const float* gating = (const float*)d_in[7];
    const float* rel    = (const float*)d_in[8];
    float* out = (float*)d_out;

    // workspace carve (~124 MB)
    char* p = (char*)d_ws;
    __bf16* xb   = (__bf16*)p;  p += (size_t)BN_ * D_ * 2;          // 18.9 MB
    __bf16* wqkt = (__bf16*)p;  p += (size_t)(2 * D_) * D_ * 2;     //  4.2 MB
    __bf16* wvt  = (__bf16*)p;  p += (size_t)D_ * D_ * 2;           //  2.1 MB
    __bf16* wpt  = (__bf16*)p;  p += (size_t)D_ * D_ * 2;           //  2.1 MB
    __bf16* qkb  = (__bf16*)p;  p += (size_t)BN_ * (2 * D_) * 2;    // 37.7 MB
    __bf16* vt   = (__bf16*)p;  p += (size_t)BN_ * D_ * 2;          // 18.9 MB  [b,h,d,m]
    __bf16* aob  = (__bf16*)p;  p += (size_t)BN_ * D_ * 2;          // 18.9 MB
    float*  pos  = (float*)p;                                       // 21.2 MB

    cast_bf16<<<(BN_ * D_) / 1024, 256, 0, stream>>>(x, xb);
    transpose_cast<<<dim3((2 * D_) / 64, D_ / 64), 256, 0, stream>>>(W_qk, wqkt, D_, 2 * D_);
    transpose_cast<<<dim3(D_ / 64, D_ / 64), 256, 0, stream>>>(W_v, wvt, D_, D_);
    transpose_cast<<<dim3(D_ / 64, D_ / 64), 256, 0, stream>>>(W_proj, wpt, D_, D_);

    // qk = x @ W_qk (bf16)
    gemm_mfma<1><<<dim3((2 * D_) / 128, BN_ / 128), 256, 0, stream>>>(
        xb, wqkt, nullptr, qkb, BN_, 2 * D_, D_);
    // vt = (x @ W_v)^T per (b,h)  (bf16, [b,h,d,m])
    gemm_mfma<2><<<dim3(D_ / 128, BN_ / 128), 256, 0, stream>>>(
        xb, wvt, nullptr, vt, BN_, D_, D_);
    // positional softmax (fp32)
    pos_softmax<<<H_ * N_, 64, 0, stream>>>(rel, W_pos, b_pos, pos);
    // MFMA gated attention
    attn_mfma<<<B_ * H_ * (N_ / 64), 256, 0, stream>>>(qkb, vt, pos, gating, aob);
    // out = ao @ W_proj + b_proj (fp32)
    gemm_mfma<0><<<dim3(D_ / 128, BN_ / 128), 256, 0, stream>>>(
        aob, wpt, b_proj, out, BN_, D_, D_);
}

// Round 4
// 683.956 us; speedup vs baseline: 3.1580x; 1.0340x over previous
//
#include <hip/hip_runtime.h>
#include <hip/hip_bf16.h>
#include <math.h>

// Problem constants (ConViT GPSA): B=16, N=576, D=1024, H=16, HD=64
#define B_ 16
#define N_ 576
#define D_ 1024
#define H_ 16
#define HD_ 64
#define BN_ (B_ * N_)   // 9216 rows
#define LOG2E 1.4426950408889634f

typedef __bf16 bf16x8 __attribute__((ext_vector_type(8)));
typedef __bf16 bf16x4 __attribute__((ext_vector_type(4)));
typedef float  f32x4  __attribute__((ext_vector_type(4)));

// ---------------------------------------------------------------------------
// cast fp32 -> bf16, 4 elems/thread
// ---------------------------------------------------------------------------
__global__ __launch_bounds__(256) void cast_bf16(
    const float* __restrict__ in, __bf16* __restrict__ out)
{
    size_t i = ((size_t)blockIdx.x * 256 + threadIdx.x) * 4;
    float4 v = *(const float4*)&in[i];
    bf16x4 o;
    o.x = (__bf16)v.x; o.y = (__bf16)v.y; o.z = (__bf16)v.z; o.w = (__bf16)v.w;
    *(bf16x4*)&out[i] = o;
}

// ---------------------------------------------------------------------------
// transpose + cast: W[K,N] fp32 -> Wt[N,K] bf16. 64x64 tiles, 256 threads.
// ---------------------------------------------------------------------------
__global__ __launch_bounds__(256) void transpose_cast(
    const float* __restrict__ W, __bf16* __restrict__ Wt, int K, int N)
{
    __shared__ float t[64][65];
    const int tid = threadIdx.x;
    const int k0 = blockIdx.y * 64, n0 = blockIdx.x * 64;
    const int r = tid >> 4, c4 = (tid & 15) << 2;
#pragma unroll
    for (int s = 0; s < 4; ++s) {
        int rr = r + (s << 4);
        float4 w = *(const float4*)&W[(size_t)(k0 + rr) * N + n0 + c4];
        t[rr][c4] = w.x; t[rr][c4 + 1] = w.y; t[rr][c4 + 2] = w.z; t[rr][c4 + 3] = w.w;
    }
    __syncthreads();
#pragma unroll
    for (int s = 0; s < 4; ++s) {
        int rr = r + (s << 4);
        bf16x4 o;
        o.x = (__bf16)t[c4 + 0][rr]; o.y = (__bf16)t[c4 + 1][rr];
        o.z = (__bf16)t[c4 + 2][rr]; o.w = (__bf16)t[c4 + 3][rr];
        *(bf16x4*)&Wt[(size_t)(n0 + rr) * K + k0 + c4] = o;
    }
}

// ---------------------------------------------------------------------------
// bf16 MFMA GEMM (m97 structure): C[M,N] = A[M,K] @ Bt[N,K]^T (+bias)
// OUTMODE: 0 = fp32 C[M,N]; 1 = bf16 C[M,N];
//          2 = bf16 V^T: vt[((row/576)*1024 + col)*576 + row%576]
// ---------------------------------------------------------------------------
template<int OUTMODE>
__global__ __launch_bounds__(256) void gemm_mfma(
    const __bf16* __restrict__ A, const __bf16* __restrict__ Bt,
    const float* __restrict__ bias, void* __restrict__ Cp,
    int M, int N, int K)
{
    __shared__ __bf16 As[128 * 32];
    __shared__ __bf16 Bs[128 * 32];
    const int tid  = threadIdx.x;
    const int lane = tid & 63;
    const int wave = tid >> 6;
    const int m0 = blockIdx.y * 128;
    const int n0 = blockIdx.x * 128;
    const int wm = (wave >> 1) * 64;
    const int wn = (wave & 1) * 64;

    const int r0 = tid >> 2, q0 = tid & 3;
    const int qs0 = q0 ^ ((r0 >> 1) & 3);
    const int r1 = r0 + 64;
    const int qs1 = q0 ^ ((r1 >> 1) & 3);
    const __bf16* srcA0 = A  + (size_t)(m0 + r0) * K + qs0 * 8;
    const __bf16* srcA1 = A  + (size_t)(m0 + r1) * K + qs1 * 8;
    const __bf16* srcB0 = Bt + (size_t)(n0 + r0) * K + qs0 * 8;
    const __bf16* srcB1 = Bt + (size_t)(n0 + r1) * K + qs1 * 8;
    __bf16* dstA0 = &As[(wave * 64) * 8];
    __bf16* dstA1 = &As[(256 + wave * 64) * 8];
    __bf16* dstB0 = &Bs[(wave * 64) * 8];
    __bf16* dstB1 = &Bs[(256 + wave * 64) * 8];

    const int fr = lane & 15, quad = lane >> 4;
    int aoff[4], boff[4];
#pragma unroll
    for (int i = 0; i < 4; ++i) {
        int row = wm + i * 16 + fr;
        aoff[i] = row * 32 + (quad ^ ((row >> 1) & 3)) * 8;
    }
#pragma unroll
    for (int j = 0; j < 4; ++j) {
        int row = wn + j * 16 + fr;
        boff[j] = row * 32 + (quad ^ ((row >> 1) & 3)) * 8;
    }

    f32x4 acc[4][4];
#pragma unroll
    for (int i = 0; i < 4; ++i)
#pragma unroll
        for (int j = 0; j < 4; ++j)
            acc[i][j] = (f32x4){0.f, 0.f, 0.f, 0.f};

    for (int k0 = 0; k0 < K; k0 += 32) {
        __syncthreads();
        __builtin_amdgcn_global_load_lds(
            (const __attribute__((address_space(1))) void*)(srcA0 + k0),
            (__attribute__((address_space(3))) void*)dstA0, 16, 0, 0);
        __builtin_amdgcn_global_load_lds(
            (const __attribute__((address_space(1))) void*)(srcA1 + k0),
            (__attribute__((address_space(3))) void*)dstA1, 16, 0, 0);
        __builtin_amdgcn_global_load_lds(
            (const __attribute__((address_space(1))) void*)(srcB0 + k0),
            (__attribute__((address_space(3))) void*)dstB0, 16, 0, 0);
        __builtin_amdgcn_global_load_lds(
            (const __attribute__((address_space(1))) void*)(srcB1 + k0),
            (__attribute__((address_space(3))) void*)dstB1, 16, 0, 0);
        __syncthreads();

        bf16x8 af[4], bfv[4];
#pragma unroll
        for (int i = 0; i < 4; ++i) af[i]  = *(const bf16x8*)&As[aoff[i]];
#pragma unroll
        for (int j = 0; j < 4; ++j) bfv[j] = *(const bf16x8*)&Bs[boff[j]];
#pragma unroll
        for (int i = 0; i < 4; ++i)
#pragma unroll
            for (int j = 0; j < 4; ++j)
                acc[i][j] = __builtin_amdgcn_mfma_f32_16x16x32_bf16(
                    af[i], bfv[j], acc[i][j], 0, 0, 0);
    }

    const int colb = n0 + wn + fr;
    const int rowb = m0 + wm + quad * 4;
#pragma unroll
    for (int j = 0; j < 4; ++j) {
        int col = colb + j * 16;
        float bv = (OUTMODE == 0 && bias) ? bias[col] : 0.0f;
#pragma unroll
        for (int i = 0; i < 4; ++i) {
            if (OUTMODE == 2) {
                int rowa = rowb + i * 16;
                int bb = rowa / 576;
                int ml = rowa - bb * 576;
                bf16x4 o4;
#pragma unroll
                for (int t = 0; t < 4; ++t) o4[t] = (__bf16)acc[i][j][t];
                *(bf16x4*)&((__bf16*)Cp)[((size_t)bb * 1024 + col) * 576 + ml] = o4;
            } else {
                int row = rowb + i * 16;
#pragma unroll
                for (int t = 0; t < 4; ++t) {
                    float v = acc[i][j][t] + bv;
                    if (OUTMODE == 1) ((__bf16*)Cp)[(size_t)(row + t) * N + col] = (__bf16)v;
                    else              ((float*)Cp)[(size_t)(row + t) * N + col] = v;
                }
            }
        }
    }
}

// ---------------------------------------------------------------------------
// pos stats: per (h,n) compute Cp = log2(g_h) - max_m(l2) - log2(sum_m exp2(l2-max))
// where l2(n,m) = LOG2E*(w0*dx + w1*dy + w2*(dx^2+dy^2)), dx = m%24-n%24,
// dy = m/24-n/24. b_pos omitted (cancels in softmax). One wave per (h,n).
// ---------------------------------------------------------------------------
__global__ __launch_bounds__(64) void pos_stats(
    const float* __restrict__ W_pos, const float* __restrict__ gating,
    float* __restrict__ Cp)
{
    const int h = blockIdx.x / N_;
    const int n = blockIdx.x % N_;
    const int lane = threadIdx.x;
    const float w0 = W_pos[h] * LOG2E, w1 = W_pos[H_ + h] * LOG2E,
                w2 = W_pos[2 * H_ + h] * LOG2E;
    const float rx = (float)(n % 24), ry = (float)(n / 24);
    float l2[9];
    float mx = -1e30f;
#pragma unroll
    for (int i = 0; i < 9; ++i) {
        int m = lane + (i << 6);
        float cx = (float)(m % 24), cy = (float)(m / 24);
        float dx = cx - rx, dy = cy - ry;
        float l = fmaf(w2, fmaf(dx, dx, dy * dy), fmaf(w0, dx, w1 * dy));
        l2[i] = l;
        mx = fmaxf(mx, l);
    }
#pragma unroll
    for (int off = 32; off; off >>= 1) mx = fmaxf(mx, __shfl_xor(mx, off, 64));
    float sum = 0.f;
#pragma unroll
    for (int i = 0; i < 9; ++i) sum += __builtin_amdgcn_exp2f(l2[i] - mx);
#pragma unroll
    for (int off = 32; off; off >>= 1) sum += __shfl_xor(sum, off, 64);
    if (lane == 0) {
        float g = 1.f / (1.f + __expf(-gating[h]));
        Cp[h * N_ + n] = __log2f(g) - mx - __log2f(sum);
    }
}

// ---------------------------------------------------------------------------
// MFMA gated attention v2. Block = (b,h); 4 waves; each wave does 9 sequential
// 16-row q-tiles (rows wave*144 + tt*16 ..). K and V^T staged once into LDS
// (one __syncthreads total); everything else wave-private.
// pos_score computed on the fly: g*pos = exp2(fc[c] + rx*u[c] + ry*v[c] + Cp')
// LDS: K 73728 + V 73728 + scratch 9216 = 156672 B -> 1 block/CU.
// ---------------------------------------------------------------------------
__global__ __launch_bounds__(256, 1) void attn_mfma2(
    const __bf16* __restrict__ qk, const __bf16* __restrict__ vt,
    const float* __restrict__ Cp, const float* __restrict__ W_pos,
    const float* __restrict__ gating, __bf16* __restrict__ ao)
{
    __shared__ __bf16 Ks[N_ * HD_];        // [n][d], phys chunk = logical ^ (n&7)
    __shared__ __bf16 Vs[HD_ * N_];        // [d][m], phys = (l&~7)|((l&7)^(d&7))
    __shared__ __bf16 Sc[4 * 16 * 72];     // per-wave scratch [16][72]

    const int bid = blockIdx.x;
    const int h = bid & 15, b = bid >> 4;
    const int tid = threadIdx.x;
    const int lane = tid & 63, wave = tid >> 6;
    const int fr = lane & 15, quad = lane >> 4;

    const __bf16* qbase = qk + (size_t)b * N_ * (2 * D_) + h * HD_;
    const __bf16* kgl   = qbase + D_;
    const __bf16* vgl   = vt + (size_t)(b * H_ + h) * HD_ * N_;

    // ---- stage K [576x64] and V^T [64x576] into LDS (swizzled) ----
#pragma unroll 2
    for (int it = 0; it < 18; ++it) {
        int s = it * 256 + tid;
        int r = s >> 3, p = s & 7;                 // K: row, phys chunk
        int l = p ^ (r & 7);
        __builtin_amdgcn_global_load_lds(
            (const __attribute__((address_space(1))) void*)(kgl + (size_t)r * (2 * D_) + l * 8),
            (__attribute__((address_space(3))) void*)&Ks[(size_t)(it * 256 + wave * 64) * 8],
            16, 0, 0);
        int d = s / 72, pv = s - d * 72;           // V: row d, phys chunk
        int lv = (pv & ~7) | ((pv & 7) ^ (d & 7));
        __builtin_amdgcn_global_load_lds(
            (const __attribute__((address_space(1))) void*)(vgl + (size_t)d * N_ + lv * 8),
            (__attribute__((address_space(3))) void*)&Vs[(size_t)(it * 256 + wave * 64) * 8],
            16, 0, 0);
    }
    __syncthreads();

    // per-h scalars
    const float g   = 1.f / (1.f + __expf(-gating[h]));
    const float omg = 1.f - g;
    const float w0 = W_pos[h] * LOG2E, w1 = W_pos[H_ + h] * LOG2E,
                w2 = W_pos[2 * H_ + h] * LOG2E;
    const float kk = 0.125f * LOG2E;               // scale*log2(e)

    // per-lane column constants: c = ct*16 + fr
    float fc[36], uu[36], vv[36];
#pragma unroll
    for (int ct = 0; ct < 36; ++ct) {
        int c = ct * 16 + fr;
        float cx = (float)(c % 24), cy = (float)(c / 24);
        fc[ct] = fmaf(w2, fmaf(cx, cx, cy * cy), fmaf(w0, cx, w1 * cy));
        uu[ct] = -2.f * w2 * cx;
        vv[ct] = -2.f * w2 * cy;
    }

    __bf16* sw = &Sc[wave * 16 * 72];

    for (int tt = 0; tt < 9; ++tt) {
        const int n0 = wave * 144 + tt * 16;

        // Q A-frags (global, read-once)
        const __bf16* qp = qbase + (size_t)(n0 + fr) * (2 * D_) + quad * 8;
        bf16x8 qf0 = *(const bf16x8*)qp;
        bf16x8 qf1 = *(const bf16x8*)(qp + 32);

        // ---- S = Q @ K^T (K from LDS) ----
        f32x4 S[36];
#pragma unroll 6
        for (int ct = 0; ct < 36; ++ct) {
            int row = ct * 16 + fr;
            int p0 = quad ^ (row & 7);
            int p1 = (4 + quad) ^ (row & 7);
            bf16x8 k0 = *(const bf16x8*)&Ks[row * 64 + p0 * 8];
            bf16x8 k1 = *(const bf16x8*)&Ks[row * 64 + p1 * 8];
            f32x4 a = (f32x4){0.f, 0.f, 0.f, 0.f};
            a = __builtin_amdgcn_mfma_f32_16x16x32_bf16(qf0, k0, a, 0, 0, 0);
            a = __builtin_amdgcn_mfma_f32_16x16x32_bf16(qf1, k1, a, 0, 0, 0);
            S[ct] = a;
        }

        // ---- per-row constants ----
        float frx[4], fry[4], Cpt[4];
#pragma unroll
        for (int t = 0; t < 4; ++t) {
            int n = n0 + quad * 4 + t;
            float rx = (float)(n % 24), ry = (float)(n / 24);
            frx[t] = rx; fry[t] = ry;
            // gr(r) = -w0*rx - w1*ry + w2*(rx^2+ry^2)
            float gr = fmaf(w2, fmaf(rx, rx, ry * ry), -fmaf(w0, rx, w1 * ry));
            Cpt[t] = Cp[h * N_ + n] + gr;
        }

        // ---- softmax (content part) ----
        float inv[4];
#pragma unroll
        for (int t = 0; t < 4; ++t) {
            float m = -1e30f;
#pragma unroll
            for (int ct = 0; ct < 36; ++ct) m = fmaxf(m, S[ct][t]);
            m = fmaxf(m, __shfl_xor(m, 1, 16));
            m = fmaxf(m, __shfl_xor(m, 2, 16));
            m = fmaxf(m, __shfl_xor(m, 4, 16));
            m = fmaxf(m, __shfl_xor(m, 8, 16));
            float km = kk * m;
            float s = 0.f;
#pragma unroll
            for (int ct = 0; ct < 36; ++ct) {
                float e = __builtin_amdgcn_exp2f(fmaf(kk, S[ct][t], -km));
                S[ct][t] = e;
                s += e;
            }
            s += __shfl_xor(s, 1, 16);
            s += __shfl_xor(s, 2, 16);
            s += __shfl_xor(s, 4, 16);
            s += __shfl_xor(s, 8, 16);
            inv[t] = omg / s;
        }

        // ---- PV: per 32-col chunk, mix P into LDS then MFMA ----
        f32x4 O[4];
#pragma unroll
        for (int dt = 0; dt < 4; ++dt) O[dt] = (f32x4){0.f, 0.f, 0.f, 0.f};
#pragma unroll 3
        for (int kb = 0; kb < 18; ++kb) {
#pragma unroll
            for (int ctl = 0; ctl < 2; ++ctl) {
                int ct = 2 * kb + ctl;
#pragma unroll
                for (int t = 0; t < 4; ++t) {
                    float pl = fmaf(frx[t], uu[ct], fc[ct]);
                    pl = fmaf(fry[t], vv[ct], pl) + Cpt[t];
                    float pval = fmaf(S[ct][t], inv[t], __builtin_amdgcn_exp2f(pl));
                    sw[(quad * 4 + t) * 72 + ctl * 16 + fr] = (__bf16)pval;
                }
            }
            // compiler inserts lgkmcnt wait for the RAW dependency
            bf16x8 pf = *(const bf16x8*)&sw[fr * 72 + quad * 8];
#pragma unroll
            for (int dt = 0; dt < 4; ++dt) {
                int d = dt * 16 + fr;
                int l = kb * 4 + quad;
                int p = (l & ~7) | ((l & 7) ^ (d & 7));
                bf16x8 vf = *(const bf16x8*)&Vs[d * 576 + p * 8];
                O[dt] = __builtin_amdgcn_mfma_f32_16x16x32_bf16(vf, pf, O[dt], 0, 0, 0);
            }
        }

        // ---- repack O via scratch, coalesced 16B stores ----
        asm volatile("s_waitcnt lgkmcnt(0)" ::: "memory");  // WAR: P reads done
#pragma unroll
        for (int dt = 0; dt < 4; ++dt) {
            bf16x4 o4;
#pragma unroll
            for (int t = 0; t < 4; ++t) o4[t] = (__bf16)O[dt][t];
            // lane holds O^T[d=dt*16+quad*4+t][n=fr] -> store [n=fr][d]
            *(bf16x4*)&sw[fr * 72 + dt * 16 + quad * 4] = o4;
        }
        asm volatile("s_waitcnt lgkmcnt(0)" ::: "memory");
#pragma unroll
        for (int s2 = 0; s2 < 2; ++s2) {
            int c   = lane + s2 * 64;
            int row = c >> 3;
            int off = (c & 7) * 8;
            bf16x8 ov = *(const bf16x8*)&sw[row * 72 + off];
            *(bf16x8*)&ao[((size_t)b * N_ + n0 + row) * D_ + h * HD_ + off] = ov;
        }
        asm volatile("s_waitcnt lgkmcnt(0)" ::: "memory");  // WAR vs next tile's P writes
    }
}

// ---------------------------------------------------------------------------
extern "C" void kernel_launch(void* const* d_in, const int* in_sizes, int n_in,
                              void* d_out, int out_size, void* d_ws, size_t ws_size,
                              hipStream_t stream)
{
    const float* x      = (const float*)d_in[0];
    const float* W_qk   = (const float*)d_in[1];
    const float* W_v    = (const float*)d_in[2];
    const float* W_proj = (const float*)d_in[3];
    const float* b_proj = (const float*)d_in[4];
    const float* W_pos  = (const float*)d_in[5];
    const float* b_pos  = (const float*)d_in[6];   // unused: cancels in softmax
    const float* gating = (const float*)d_in[7];
    const float* rel    = (const float*)d_in[8];   // unused: computed on the fly
    (void)b_pos; (void)rel;
    float* out = (float*)d_out;

    // workspace carve (~103 MB)
    char* p = (char*)d_ws;
    __bf16* xb   = (__bf16*)p;  p += (size_t)BN_ * D_ * 2;          // 18.9 MB
    __bf16* wqkt = (__bf16*)p;  p += (size_t)(2 * D_) * D_ * 2;     //  4.2 MB
    __bf16* wvt  = (__bf16*)p;  p += (size_t)D_ * D_ * 2;           //  2.1 MB
    __bf16* wpt  = (__bf16*)p;  p += (size_t)D_ * D_ * 2;           //  2.1 MB
    __bf16* qkb  = (__bf16*)p;  p += (size_t)BN_ * (2 * D_) * 2;    // 37.7 MB
    __bf16* vt   = (__bf16*)p;  p += (size_t)BN_ * D_ * 2;          // 18.9 MB  [b,h,d,m]
    __bf16* aob  = (__bf16*)p;  p += (size_t)BN_ * D_ * 2;          // 18.9 MB
    float*  Cp   = (float*)p;                                       // 36 KB

    cast_bf16<<<(BN_ * D_) / 1024, 256, 0, stream>>>(x, xb);
    transpose_cast<<<dim3((2 * D_) / 64, D_ / 64), 256, 0, stream>>>(W_qk, wqkt, D_, 2 * D_);
    transpose_cast<<<dim3(D_ / 64, D_ / 64), 256, 0, stream>>>(W_v, wvt, D_, D_);
    transpose_cast<<<dim3(D_ / 64, D_ / 64), 256, 0, stream>>>(W_proj, wpt, D_, D_);

    gemm_mfma<1><<<dim3((2 * D_) / 128, BN_ / 128), 256, 0, stream>>>(
        xb, wqkt, nullptr, qkb, BN_, 2 * D_, D_);
    gemm_mfma<2><<<dim3(D_ / 128, BN_ / 128), 256, 0, stream>>>(
        xb, wvt, nullptr, vt, BN_, D_, D_);
    pos_stats<<<H_ * N_, 64, 0, stream>>>(W_pos, gating, Cp);
    attn_mfma2<<<B_ * H_, 256, 0, stream>>>(qkb, vt, Cp, W_pos, gating, aob);
    gemm_mfma<0><<<dim3(D_ / 128, BN_ / 128), 256, 0, stream>>>(
        aob, wpt, b_proj, out, BN_, D_, D_);
}

// Round 5
// 349.522 us; speedup vs baseline: 6.1798x; 1.9568x over previous
//
#include <hip/hip_runtime.h>
#include <hip/hip_bf16.h>
#include <math.h>

// Problem constants (ConViT GPSA): B=16, N=576, D=1024, H=16, HD=64
#define B_ 16
#define N_ 576
#define D_ 1024
#define H_ 16
#define HD_ 64
#define BN_ (B_ * N_)   // 9216 rows
#define LOG2E 1.4426950408889634f

typedef __bf16 bf16x8 __attribute__((ext_vector_type(8)));
typedef __bf16 bf16x4 __attribute__((ext_vector_type(4)));
typedef float  f32x4  __attribute__((ext_vector_type(4)));

// ---------------------------------------------------------------------------
// cast fp32 -> bf16, 4 elems/thread
// ---------------------------------------------------------------------------
__global__ __launch_bounds__(256) void cast_bf16(
    const float* __restrict__ in, __bf16* __restrict__ out)
{
    size_t i = ((size_t)blockIdx.x * 256 + threadIdx.x) * 4;
    float4 v = *(const float4*)&in[i];
    bf16x4 o;
    o.x = (__bf16)v.x; o.y = (__bf16)v.y; o.z = (__bf16)v.z; o.w = (__bf16)v.w;
    *(bf16x4*)&out[i] = o;
}

// ---------------------------------------------------------------------------
// transpose + cast: W[K,N] fp32 -> Wt[N,K] bf16. 64x64 tiles, 256 threads.
// ---------------------------------------------------------------------------
__global__ __launch_bounds__(256) void transpose_cast(
    const float* __restrict__ W, __bf16* __restrict__ Wt, int K, int N)
{
    __shared__ float t[64][65];
    const int tid = threadIdx.x;
    const int k0 = blockIdx.y * 64, n0 = blockIdx.x * 64;
    const int r = tid >> 4, c4 = (tid & 15) << 2;
#pragma unroll
    for (int s = 0; s < 4; ++s) {
        int rr = r + (s << 4);
        float4 w = *(const float4*)&W[(size_t)(k0 + rr) * N + n0 + c4];
        t[rr][c4] = w.x; t[rr][c4 + 1] = w.y; t[rr][c4 + 2] = w.z; t[rr][c4 + 3] = w.w;
    }
    __syncthreads();
#pragma unroll
    for (int s = 0; s < 4; ++s) {
        int rr = r + (s << 4);
        bf16x4 o;
        o.x = (__bf16)t[c4 + 0][rr]; o.y = (__bf16)t[c4 + 1][rr];
        o.z = (__bf16)t[c4 + 2][rr]; o.w = (__bf16)t[c4 + 3][rr];
        *(bf16x4*)&Wt[(size_t)(n0 + rr) * K + k0 + c4] = o;
    }
}

// ---------------------------------------------------------------------------
// bf16 MFMA GEMM (m97 structure): C[M,N] = A[M,K] @ Bt[N,K]^T (+bias)
// OUTMODE: 0 = fp32 C[M,N]; 1 = bf16 C[M,N];
//          2 = bf16 V^T: vt[((row/576)*1024 + col)*576 + row%576]
// ---------------------------------------------------------------------------
template<int OUTMODE>
__global__ __launch_bounds__(256) void gemm_mfma(
    const __bf16* __restrict__ A, const __bf16* __restrict__ Bt,
    const float* __restrict__ bias, void* __restrict__ Cp,
    int M, int N, int K)
{
    __shared__ __bf16 As[128 * 32];
    __shared__ __bf16 Bs[128 * 32];
    const int tid  = threadIdx.x;
    const int lane = tid & 63;
    const int wave = tid >> 6;
    const int m0 = blockIdx.y * 128;
    const int n0 = blockIdx.x * 128;
    const int wm = (wave >> 1) * 64;
    const int wn = (wave & 1) * 64;

    const int r0 = tid >> 2, q0 = tid & 3;
    const int qs0 = q0 ^ ((r0 >> 1) & 3);
    const int r1 = r0 + 64;
    const int qs1 = q0 ^ ((r1 >> 1) & 3);
    const __bf16* srcA0 = A  + (size_t)(m0 + r0) * K + qs0 * 8;
    const __bf16* srcA1 = A  + (size_t)(m0 + r1) * K + qs1 * 8;
    const __bf16* srcB0 = Bt + (size_t)(n0 + r0) * K + qs0 * 8;
    const __bf16* srcB1 = Bt + (size_t)(n0 + r1) * K + qs1 * 8;
    __bf16* dstA0 = &As[(wave * 64) * 8];
    __bf16* dstA1 = &As[(256 + wave * 64) * 8];
    __bf16* dstB0 = &Bs[(wave * 64) * 8];
    __bf16* dstB1 = &Bs[(256 + wave * 64) * 8];

    const int fr = lane & 15, quad = lane >> 4;
    int aoff[4], boff[4];
#pragma unroll
    for (int i = 0; i < 4; ++i) {
        int row = wm + i * 16 + fr;
        aoff[i] = row * 32 + (quad ^ ((row >> 1) & 3)) * 8;
    }
#pragma unroll
    for (int j = 0; j < 4; ++j) {
        int row = wn + j * 16 + fr;
        boff[j] = row * 32 + (quad ^ ((row >> 1) & 3)) * 8;
    }

    f32x4 acc[4][4];
#pragma unroll
    for (int i = 0; i < 4; ++i)
#pragma unroll
        for (int j = 0; j < 4; ++j)
            acc[i][j] = (f32x4){0.f, 0.f, 0.f, 0.f};

    for (int k0 = 0; k0 < K; k0 += 32) {
        __syncthreads();
        __builtin_amdgcn_global_load_lds(
            (const __attribute__((address_space(1))) void*)(srcA0 + k0),
            (__attribute__((address_space(3))) void*)dstA0, 16, 0, 0);
        __builtin_amdgcn_global_load_lds(
            (const __attribute__((address_space(1))) void*)(srcA1 + k0),
            (__attribute__((address_space(3))) void*)dstA1, 16, 0, 0);
        __builtin_amdgcn_global_load_lds(
            (const __attribute__((address_space(1))) void*)(srcB0 + k0),
            (__attribute__((address_space(3))) void*)dstB0, 16, 0, 0);
        __builtin_amdgcn_global_load_lds(
            (const __attribute__((address_space(1))) void*)(srcB1 + k0),
            (__attribute__((address_space(3))) void*)dstB1, 16, 0, 0);
        __syncthreads();

        bf16x8 af[4], bfv[4];
#pragma unroll
        for (int i = 0; i < 4; ++i) af[i]  = *(const bf16x8*)&As[aoff[i]];
#pragma unroll
        for (int j = 0; j < 4; ++j) bfv[j] = *(const bf16x8*)&Bs[boff[j]];
#pragma unroll
        for (int i = 0; i < 4; ++i)
#pragma unroll
            for (int j = 0; j < 4; ++j)
                acc[i][j] = __builtin_amdgcn_mfma_f32_16x16x32_bf16(
                    af[i], bfv[j], acc[i][j], 0, 0, 0);
    }

    const int colb = n0 + wn + fr;
    const int rowb = m0 + wm + quad * 4;
#pragma unroll
    for (int j = 0; j < 4; ++j) {
        int col = colb + j * 16;
        float bv = (OUTMODE == 0 && bias) ? bias[col] : 0.0f;
#pragma unroll
        for (int i = 0; i < 4; ++i) {
            if (OUTMODE == 2) {
                int rowa = rowb + i * 16;
                int bb = rowa / 576;
                int ml = rowa - bb * 576;
                bf16x4 o4;
#pragma unroll
                for (int t = 0; t < 4; ++t) o4[t] = (__bf16)acc[i][j][t];
                *(bf16x4*)&((__bf16*)Cp)[((size_t)bb * 1024 + col) * 576 + ml] = o4;
            } else {
                int row = rowb + i * 16;
#pragma unroll
                for (int t = 0; t < 4; ++t) {
                    float v = acc[i][j][t] + bv;
                    if (OUTMODE == 1) ((__bf16*)Cp)[(size_t)(row + t) * N + col] = (__bf16)v;
                    else              ((float*)Cp)[(size_t)(row + t) * N + col] = v;
                }
            }
        }
    }
}

// ---------------------------------------------------------------------------
// pos stats: per (h,n) compute Cp = log2(g_h) - max_m(l2) - log2(sum_m exp2(l2-max))
// where l2(n,m) = LOG2E*(w0*dx + w1*dy + w2*(dx^2+dy^2)), dx = m%24-n%24,
// dy = m/24-n/24. b_pos omitted (cancels in softmax). One wave per (h,n).
// ---------------------------------------------------------------------------
__global__ __launch_bounds__(64) void pos_stats(
    const float* __restrict__ W_pos, const float* __restrict__ gating,
    float* __restrict__ Cp)
{
    const int h = blockIdx.x / N_;
    const int n = blockIdx.x % N_;
    const int lane = threadIdx.x;
    const float w0 = W_pos[h] * LOG2E, w1 = W_pos[H_ + h] * LOG2E,
                w2 = W_pos[2 * H_ + h] * LOG2E;
    const float rx = (float)(n % 24), ry = (float)(n / 24);
    float l2[9];
    float mx = -1e30f;
#pragma unroll
    for (int i = 0; i < 9; ++i) {
        int m = lane + (i << 6);
        float cx = (float)(m % 24), cy = (float)(m / 24);
        float dx = cx - rx, dy = cy - ry;
        float l = fmaf(w2, fmaf(dx, dx, dy * dy), fmaf(w0, dx, w1 * dy));
        l2[i] = l;
        mx = fmaxf(mx, l);
    }
#pragma unroll
    for (int off = 32; off; off >>= 1) mx = fmaxf(mx, __shfl_xor(mx, off, 64));
    float sum = 0.f;
#pragma unroll
    for (int i = 0; i < 9; ++i) sum += __builtin_amdgcn_exp2f(l2[i] - mx);
#pragma unroll
    for (int off = 32; off; off >>= 1) sum += __shfl_xor(sum, off, 64);
    if (lane == 0) {
        float g = 1.f / (1.f + __expf(-gating[h]));
        Cp[h * N_ + n] = __log2f(g) - mx - __log2f(sum);
    }
}

// ---------------------------------------------------------------------------
// MFMA gated attention v3. Block = (b,h); 4 waves; each wave does 9 sequential
// 16-row q-tiles. K and V^T staged once into LDS (one __syncthreads total).
// ALL loops touching S/fc/uu/vv are FULLY unrolled so arrays live in registers
// (R4 used partial unrolls -> scratch spills -> 1.4 GB of HBM spill traffic).
// ~300 VGPRs, 1 wave/SIMD (grid = 256 = 1 block/CU anyway).
// LDS: K 73728 + V 73728 + scratch 9216 = 156672 B.
// ---------------------------------------------------------------------------
__global__ __launch_bounds__(256, 1) void attn_mfma2(
    const __bf16* __restrict__ qk, const __bf16* __restrict__ vt,
    const float* __restrict__ Cp, const float* __restrict__ W_pos,
    const float* __restrict__ gating, __bf16* __restrict__ ao)
{
    __shared__ __bf16 Ks[N_ * HD_];        // [n][d], phys chunk = logical ^ (n&7)
    __shared__ __bf16 Vs[HD_ * N_];        // [d][m], phys = (l&~7)|((l&7)^(d&7))
    __shared__ __bf16 Sc[4 * 16 * 72];     // per-wave scratch [16][72]

    const int bid = blockIdx.x;
    const int h = bid & 15, b = bid >> 4;
    const int tid = threadIdx.x;
    const int lane = tid & 63, wave = tid >> 6;
    const int fr = lane & 15, quad = lane >> 4;

    const __bf16* qbase = qk + (size_t)b * N_ * (2 * D_) + h * HD_;
    const __bf16* kgl   = qbase + D_;
    const __bf16* vgl   = vt + (size_t)(b * H_ + h) * HD_ * N_;

    // ---- stage K [576x64] and V^T [64x576] into LDS (swizzled) ----
#pragma unroll 2
    for (int it = 0; it < 18; ++it) {
        int s = it * 256 + tid;
        int r = s >> 3, p = s & 7;                 // K: row, phys chunk
        int l = p ^ (r & 7);
        __builtin_amdgcn_global_load_lds(
            (const __attribute__((address_space(1))) void*)(kgl + (size_t)r * (2 * D_) + l * 8),
            (__attribute__((address_space(3))) void*)&Ks[(size_t)(it * 256 + wave * 64) * 8],
            16, 0, 0);
        int d = s / 72, pv = s - d * 72;           // V: row d, phys chunk
        int lv = (pv & ~7) | ((pv & 7) ^ (d & 7));
        __builtin_amdgcn_global_load_lds(
            (const __attribute__((address_space(1))) void*)(vgl + (size_t)d * N_ + lv * 8),
            (__attribute__((address_space(3))) void*)&Vs[(size_t)(it * 256 + wave * 64) * 8],
            16, 0, 0);
    }
    __syncthreads();

    // per-h scalars
    const float g   = 1.f / (1.f + __expf(-gating[h]));
    const float omg = 1.f - g;
    const float w0 = W_pos[h] * LOG2E, w1 = W_pos[H_ + h] * LOG2E,
                w2 = W_pos[2 * H_ + h] * LOG2E;
    const float kk = 0.125f * LOG2E;               // scale*log2(e)

    // per-lane column constants: c = ct*16 + fr  (fully unrolled -> registers)
    float fc[36], uu[36], vv[36];
#pragma unroll
    for (int ct = 0; ct < 36; ++ct) {
        int c = ct * 16 + fr;
        float cx = (float)(c % 24), cy = (float)(c / 24);
        fc[ct] = fmaf(w2, fmaf(cx, cx, cy * cy), fmaf(w0, cx, w1 * cy));
        uu[ct] = -2.f * w2 * cx;
        vv[ct] = -2.f * w2 * cy;
    }

    __bf16* sw = &Sc[wave * 16 * 72];

    for (int tt = 0; tt < 9; ++tt) {
        const int n0 = wave * 144 + tt * 16;

        // Q A-frags (global, read-once)
        const __bf16* qp = qbase + (size_t)(n0 + fr) * (2 * D_) + quad * 8;
        bf16x8 qf0 = *(const bf16x8*)qp;
        bf16x8 qf1 = *(const bf16x8*)(qp + 32);

        // ---- S = Q @ K^T (K from LDS); FULL unroll, S in registers ----
        f32x4 S[36];
#pragma unroll
        for (int ct = 0; ct < 36; ++ct) {
            int row = ct * 16 + fr;
            int p0 = quad ^ (row & 7);
            int p1 = (4 + quad) ^ (row & 7);
            bf16x8 k0 = *(const bf16x8*)&Ks[row * 64 + p0 * 8];
            bf16x8 k1 = *(const bf16x8*)&Ks[row * 64 + p1 * 8];
            f32x4 a = (f32x4){0.f, 0.f, 0.f, 0.f};
            a = __builtin_amdgcn_mfma_f32_16x16x32_bf16(qf0, k0, a, 0, 0, 0);
            a = __builtin_amdgcn_mfma_f32_16x16x32_bf16(qf1, k1, a, 0, 0, 0);
            S[ct] = a;
        }

        // ---- per-row constants ----
        float frx[4], fry[4], Cpt[4];
#pragma unroll
        for (int t = 0; t < 4; ++t) {
            int n = n0 + quad * 4 + t;
            float rx = (float)(n % 24), ry = (float)(n / 24);
            frx[t] = rx; fry[t] = ry;
            float gr = fmaf(w2, fmaf(rx, rx, ry * ry), -fmaf(w0, rx, w1 * ry));
            Cpt[t] = Cp[h * N_ + n] + gr;
        }

        // ---- softmax (content part), FULL unroll ----
        float inv[4];
#pragma unroll
        for (int t = 0; t < 4; ++t) {
            float m = -1e30f;
#pragma unroll
            for (int ct = 0; ct < 36; ++ct) m = fmaxf(m, S[ct][t]);
            m = fmaxf(m, __shfl_xor(m, 1, 16));
            m = fmaxf(m, __shfl_xor(m, 2, 16));
            m = fmaxf(m, __shfl_xor(m, 4, 16));
            m = fmaxf(m, __shfl_xor(m, 8, 16));
            float km = kk * m;
            float s = 0.f;
#pragma unroll
            for (int ct = 0; ct < 36; ++ct) {
                float e = __builtin_amdgcn_exp2f(fmaf(kk, S[ct][t], -km));
                S[ct][t] = e;
                s += e;
            }
            s += __shfl_xor(s, 1, 16);
            s += __shfl_xor(s, 2, 16);
            s += __shfl_xor(s, 4, 16);
            s += __shfl_xor(s, 8, 16);
            inv[t] = omg / s;
        }

        // ---- PV: per 32-col chunk, mix P into LDS then MFMA; FULL unroll ----
        f32x4 O[4];
#pragma unroll
        for (int dt = 0; dt < 4; ++dt) O[dt] = (f32x4){0.f, 0.f, 0.f, 0.f};
#pragma unroll
        for (int kb = 0; kb < 18; ++kb) {
#pragma unroll
            for (int ctl = 0; ctl < 2; ++ctl) {
                int ct = 2 * kb + ctl;
#pragma unroll
                for (int t = 0; t < 4; ++t) {
                    float pl = fmaf(frx[t], uu[ct], fc[ct]);
                    pl = fmaf(fry[t], vv[ct], pl) + Cpt[t];
                    float pval = fmaf(S[ct][t], inv[t], __builtin_amdgcn_exp2f(pl));
                    sw[(quad * 4 + t) * 72 + ctl * 16 + fr] = (__bf16)pval;
                }
            }
            bf16x8 pf = *(const bf16x8*)&sw[fr * 72 + quad * 8];
#pragma unroll
            for (int dt = 0; dt < 4; ++dt) {
                int d = dt * 16 + fr;
                int l = kb * 4 + quad;
                int p = (l & ~7) | ((l & 7) ^ (d & 7));
                bf16x8 vf = *(const bf16x8*)&Vs[d * 576 + p * 8];
                O[dt] = __builtin_amdgcn_mfma_f32_16x16x32_bf16(vf, pf, O[dt], 0, 0, 0);
            }
        }

        // ---- repack O via scratch, coalesced 16B stores ----
        asm volatile("s_waitcnt lgkmcnt(0)" ::: "memory");  // WAR: P reads done
#pragma unroll
        for (int dt = 0; dt < 4; ++dt) {
            bf16x4 o4;
#pragma unroll
            for (int t = 0; t < 4; ++t) o4[t] = (__bf16)O[dt][t];
            *(bf16x4*)&sw[fr * 72 + dt * 16 + quad * 4] = o4;
        }
        asm volatile("s_waitcnt lgkmcnt(0)" ::: "memory");
#pragma unroll
        for (int s2 = 0; s2 < 2; ++s2) {
            int c   = lane + s2 * 64;
            int row = c >> 3;
            int off = (c & 7) * 8;
            bf16x8 ov = *(const bf16x8*)&sw[row * 72 + off];
            *(bf16x8*)&ao[((size_t)b * N_ + n0 + row) * D_ + h * HD_ + off] = ov;
        }
        asm volatile("s_waitcnt lgkmcnt(0)" ::: "memory");  // WAR vs next tile
    }
}

// ---------------------------------------------------------------------------
extern "C" void kernel_launch(void* const* d_in, const int* in_sizes, int n_in,
                              void* d_out, int out_size, void* d_ws, size_t ws_size,
                              hipStream_t stream)
{
    const float* x      = (const float*)d_in[0];
    const float* W_qk   = (const float*)d_in[1];
    const float* W_v    = (const float*)d_in[2];
    const float* W_proj = (const float*)d_in[3];
    const float* b_proj = (const float*)d_in[4];
    const float* W_pos  = (const float*)d_in[5];
    const float* b_pos  = (const float*)d_in[6];   // unused: cancels in softmax
    const float* gating = (const float*)d_in[7];
    const float* rel    = (const float*)d_in[8];   // unused: computed on the fly
    (void)b_pos; (void)rel;
    float* out = (float*)d_out;

    // workspace carve (~103 MB)
    char* p = (char*)d_ws;
    __bf16* xb   = (__bf16*)p;  p += (size_t)BN_ * D_ * 2;          // 18.9 MB
    __bf16* wqkt = (__bf16*)p;  p += (size_t)(2 * D_) * D_ * 2;     //  4.2 MB
    __bf16* wvt  = (__bf16*)p;  p += (size_t)D_ * D_ * 2;           //  2.1 MB
    __bf16* wpt  = (__bf16*)p;  p += (size_t)D_ * D_ * 2;           //  2.1 MB
    __bf16* qkb  = (__bf16*)p;  p += (size_t)BN_ * (2 * D_) * 2;    // 37.7 MB
    __bf16* vt   = (__bf16*)p;  p += (size_t)BN_ * D_ * 2;          // 18.9 MB  [b,h,d,m]
    __bf16* aob  = (__bf16*)p;  p += (size_t)BN_ * D_ * 2;          // 18.9 MB
    float*  Cp   = (float*)p;                                       // 36 KB

    cast_bf16<<<(BN_ * D_) / 1024, 256, 0, stream>>>(x, xb);
    transpose_cast<<<dim3((2 * D_) / 64, D_ / 64), 256, 0, stream>>>(W_qk, wqkt, D_, 2 * D_);
    transpose_cast<<<dim3(D_ / 64, D_ / 64), 256, 0, stream>>>(W_v, wvt, D_, D_);
    transpose_cast<<<dim3(D_ / 64, D_ / 64), 256, 0, stream>>>(W_proj, wpt, D_, D_);

    gemm_mfma<1><<<dim3((2 * D_) / 128, BN_ / 128), 256, 0, stream>>>(
        xb, wqkt, nullptr, qkb, BN_, 2 * D_, D_);
    gemm_mfma<2><<<dim3(D_ / 128, BN_ / 128), 256, 0, stream>>>(
        xb, wvt, nullptr, vt, BN_, D_, D_);
    pos_stats<<<H_ * N_, 64, 0, stream>>>(W_pos, gating, Cp);
    attn_mfma2<<<B_ * H_, 256, 0, stream>>>(qkb, vt, Cp, W_pos, gating, aob);
    gemm_mfma<0><<<dim3(D_ / 128, BN_ / 128), 256, 0, stream>>>(
        aob, wpt, b_proj, out, BN_, D_, D_);
}

// Round 6
// 339.698 us; speedup vs baseline: 6.3585x; 1.0289x over previous
//
#include <hip/hip_runtime.h>
#include <hip/hip_bf16.h>
#include <math.h>

// Problem constants (ConViT GPSA): B=16, N=576, D=1024, H=16, HD=64
#define B_ 16
#define N_ 576
#define D_ 1024
#define H_ 16
#define HD_ 64
#define BN_ (B_ * N_)   // 9216 rows
#define LOG2E 1.4426950408889634f

typedef __bf16 bf16x8 __attribute__((ext_vector_type(8)));
typedef __bf16 bf16x4 __attribute__((ext_vector_type(4)));
typedef float  f32x4  __attribute__((ext_vector_type(4)));

// ---------------------------------------------------------------------------
// cast fp32 -> bf16, 4 elems/thread
// ---------------------------------------------------------------------------
__global__ __launch_bounds__(256) void cast_bf16(
    const float* __restrict__ in, __bf16* __restrict__ out)
{
    size_t i = ((size_t)blockIdx.x * 256 + threadIdx.x) * 4;
    float4 v = *(const float4*)&in[i];
    bf16x4 o;
    o.x = (__bf16)v.x; o.y = (__bf16)v.y; o.z = (__bf16)v.z; o.w = (__bf16)v.w;
    *(bf16x4*)&out[i] = o;
}

// ---------------------------------------------------------------------------
// transpose + cast: W[K,N] fp32 -> Wt[N,K] bf16. 64x64 tiles, 256 threads.
// ---------------------------------------------------------------------------
__global__ __launch_bounds__(256) void transpose_cast(
    const float* __restrict__ W, __bf16* __restrict__ Wt, int K, int N)
{
    __shared__ float t[64][65];
    const int tid = threadIdx.x;
    const int k0 = blockIdx.y * 64, n0 = blockIdx.x * 64;
    const int r = tid >> 4, c4 = (tid & 15) << 2;
#pragma unroll
    for (int s = 0; s < 4; ++s) {
        int rr = r + (s << 4);
        float4 w = *(const float4*)&W[(size_t)(k0 + rr) * N + n0 + c4];
        t[rr][c4] = w.x; t[rr][c4 + 1] = w.y; t[rr][c4 + 2] = w.z; t[rr][c4 + 3] = w.w;
    }
    __syncthreads();
#pragma unroll
    for (int s = 0; s < 4; ++s) {
        int rr = r + (s << 4);
        bf16x4 o;
        o.x = (__bf16)t[c4 + 0][rr]; o.y = (__bf16)t[c4 + 1][rr];
        o.z = (__bf16)t[c4 + 2][rr]; o.w = (__bf16)t[c4 + 3][rr];
        *(bf16x4*)&Wt[(size_t)(n0 + rr) * K + k0 + c4] = o;
    }
}

// ---------------------------------------------------------------------------
// bf16 MFMA GEMM (m97 structure): C[M,N] = A[M,K] @ Bt[N,K]^T (+bias)
// OUTMODE: 0 = fp32 C[M,N]; 1 = bf16 C[M,N];
//          3 = fused qk|v: cols 0..2047 -> bf16 qkb[M][2048] (Cp);
//              cols 2048..3071 -> vt[b][d][m] transposed (Cp2). N must be 3072.
// ---------------------------------------------------------------------------
template<int OUTMODE>
__global__ __launch_bounds__(256) void gemm_mfma(
    const __bf16* __restrict__ A, const __bf16* __restrict__ Bt,
    const float* __restrict__ bias, void* __restrict__ Cp, void* __restrict__ Cp2,
    int M, int N, int K)
{
    __shared__ __bf16 As[128 * 32];
    __shared__ __bf16 Bs[128 * 32];
    const int tid  = threadIdx.x;
    const int lane = tid & 63;
    const int wave = tid >> 6;
    const int m0 = blockIdx.y * 128;
    const int n0 = blockIdx.x * 128;
    const int wm = (wave >> 1) * 64;
    const int wn = (wave & 1) * 64;

    const int r0 = tid >> 2, q0 = tid & 3;
    const int qs0 = q0 ^ ((r0 >> 1) & 3);
    const int r1 = r0 + 64;
    const int qs1 = q0 ^ ((r1 >> 1) & 3);
    const __bf16* srcA0 = A  + (size_t)(m0 + r0) * K + qs0 * 8;
    const __bf16* srcA1 = A  + (size_t)(m0 + r1) * K + qs1 * 8;
    const __bf16* srcB0 = Bt + (size_t)(n0 + r0) * K + qs0 * 8;
    const __bf16* srcB1 = Bt + (size_t)(n0 + r1) * K + qs1 * 8;
    __bf16* dstA0 = &As[(wave * 64) * 8];
    __bf16* dstA1 = &As[(256 + wave * 64) * 8];
    __bf16* dstB0 = &Bs[(wave * 64) * 8];
    __bf16* dstB1 = &Bs[(256 + wave * 64) * 8];

    const int fr = lane & 15, quad = lane >> 4;
    int aoff[4], boff[4];
#pragma unroll
    for (int i = 0; i < 4; ++i) {
        int row = wm + i * 16 + fr;
        aoff[i] = row * 32 + (quad ^ ((row >> 1) & 3)) * 8;
    }
#pragma unroll
    for (int j = 0; j < 4; ++j) {
        int row = wn + j * 16 + fr;
        boff[j] = row * 32 + (quad ^ ((row >> 1) & 3)) * 8;
    }

    f32x4 acc[4][4];
#pragma unroll
    for (int i = 0; i < 4; ++i)
#pragma unroll
        for (int j = 0; j < 4; ++j)
            acc[i][j] = (f32x4){0.f, 0.f, 0.f, 0.f};

    for (int k0 = 0; k0 < K; k0 += 32) {
        __syncthreads();
        __builtin_amdgcn_global_load_lds(
            (const __attribute__((address_space(1))) void*)(srcA0 + k0),
            (__attribute__((address_space(3))) void*)dstA0, 16, 0, 0);
        __builtin_amdgcn_global_load_lds(
            (const __attribute__((address_space(1))) void*)(srcA1 + k0),
            (__attribute__((address_space(3))) void*)dstA1, 16, 0, 0);
        __builtin_amdgcn_global_load_lds(
            (const __attribute__((address_space(1))) void*)(srcB0 + k0),
            (__attribute__((address_space(3))) void*)dstB0, 16, 0, 0);
        __builtin_amdgcn_global_load_lds(
            (const __attribute__((address_space(1))) void*)(srcB1 + k0),
            (__attribute__((address_space(3))) void*)dstB1, 16, 0, 0);
        __syncthreads();

        bf16x8 af[4], bfv[4];
#pragma unroll
        for (int i = 0; i < 4; ++i) af[i]  = *(const bf16x8*)&As[aoff[i]];
#pragma unroll
        for (int j = 0; j < 4; ++j) bfv[j] = *(const bf16x8*)&Bs[boff[j]];
#pragma unroll
        for (int i = 0; i < 4; ++i)
#pragma unroll
            for (int j = 0; j < 4; ++j)
                acc[i][j] = __builtin_amdgcn_mfma_f32_16x16x32_bf16(
                    af[i], bfv[j], acc[i][j], 0, 0, 0);
    }

    // epilogue: C/D layout col=lane&15, row=quad*4+reg
    const int colb = n0 + wn + fr;
    const int rowb = m0 + wm + quad * 4;
#pragma unroll
    for (int j = 0; j < 4; ++j) {
        int col = colb + j * 16;
        float bv = (OUTMODE == 0 && bias) ? bias[col] : 0.0f;
#pragma unroll
        for (int i = 0; i < 4; ++i) {
            int row = rowb + i * 16;
            if (OUTMODE == 3) {
                if (col < 2048) {       // block-uniform branch (n0 mult of 128)
#pragma unroll
                    for (int t = 0; t < 4; ++t)
                        ((__bf16*)Cp)[(size_t)(row + t) * 2048 + col] = (__bf16)acc[i][j][t];
                } else {
                    int bb = row / 576;
                    int ml = row - bb * 576;   // ml%4==0, never crosses batch
                    bf16x4 o4;
#pragma unroll
                    for (int t = 0; t < 4; ++t) o4[t] = (__bf16)acc[i][j][t];
                    *(bf16x4*)&((__bf16*)Cp2)[((size_t)bb * 1024 + (col - 2048)) * 576 + ml] = o4;
                }
            } else {
#pragma unroll
                for (int t = 0; t < 4; ++t) {
                    float v = acc[i][j][t] + bv;
                    if (OUTMODE == 1) ((__bf16*)Cp)[(size_t)(row + t) * N + col] = (__bf16)v;
                    else              ((float*)Cp)[(size_t)(row + t) * N + col] = v;
                }
            }
        }
    }
}

// ---------------------------------------------------------------------------
// pos stats: per (h,n) Cp = log2(g_h) - max_m(l2) - log2(sum_m exp2(l2-max))
// l2(n,m) = LOG2E*(w0*dx + w1*dy + w2*(dx^2+dy^2)); b_pos cancels in softmax.
// ---------------------------------------------------------------------------
__global__ __launch_bounds__(64) void pos_stats(
    const float* __restrict__ W_pos, const float* __restrict__ gating,
    float* __restrict__ Cp)
{
    const int h = blockIdx.x / N_;
    const int n = blockIdx.x % N_;
    const int lane = threadIdx.x;
    const float w0 = W_pos[h] * LOG2E, w1 = W_pos[H_ + h] * LOG2E,
                w2 = W_pos[2 * H_ + h] * LOG2E;
    const float rx = (float)(n % 24), ry = (float)(n / 24);
    float l2[9];
    float mx = -1e30f;
#pragma unroll
    for (int i = 0; i < 9; ++i) {
        int m = lane + (i << 6);
        float cx = (float)(m % 24), cy = (float)(m / 24);
        float dx = cx - rx, dy = cy - ry;
        float l = fmaf(w2, fmaf(dx, dx, dy * dy), fmaf(w0, dx, w1 * dy));
        l2[i] = l;
        mx = fmaxf(mx, l);
    }
#pragma unroll
    for (int off = 32; off; off >>= 1) mx = fmaxf(mx, __shfl_xor(mx, off, 64));
    float sum = 0.f;
#pragma unroll
    for (int i = 0; i < 9; ++i) sum += __builtin_amdgcn_exp2f(l2[i] - mx);
#pragma unroll
    for (int off = 32; off; off >>= 1) sum += __shfl_xor(sum, off, 64);
    if (lane == 0) {
        float g = 1.f / (1.f + __expf(-gating[h]));
        Cp[h * N_ + n] = __log2f(g) - mx - __log2f(sum);
    }
}

// ---------------------------------------------------------------------------
// MFMA gated attention v4. Block = (b,h), 512 threads = 8 waves (2/SIMD for
// latency hiding; R5 at 4 waves was latency-bound at VALUBusy 33%).
// K and V^T staged once into LDS; waves take q-tiles tt = wave, wave+8, ...
// (waves w and w+4 share a SIMD with 5+4 tiles -> balanced).
// Scratch stride 48 bf16 (16B-aligned, bank-balanced), two-pass O repack.
// LDS: K 73728 + V 73728 + Sc 12288 = 159744 B. VGPR capped 256 (R5: 236).
// ---------------------------------------------------------------------------
__global__ __launch_bounds__(512, 2) void attn_mfma3(
    const __bf16* __restrict__ qk, const __bf16* __restrict__ vt,
    const float* __restrict__ Cp, const float* __restrict__ W_pos,
    const float* __restrict__ gating, __bf16* __restrict__ ao)
{
    __shared__ __bf16 Ks[N_ * HD_];        // [n][d], phys chunk = logical ^ (n&7)
    __shared__ __bf16 Vs[HD_ * N_];        // [d][m], phys = (l&~7)|((l&7)^(d&7))
    __shared__ __bf16 Sc[8 * 16 * 48];     // per-wave scratch [16][48]

    const int bid = blockIdx.x;
    const int h = bid & 15, b = bid >> 4;
    const int tid = threadIdx.x;
    const int lane = tid & 63, wave = tid >> 6;   // 0..7
    const int fr = lane & 15, quad = lane >> 4;

    const __bf16* qbase = qk + (size_t)b * N_ * (2 * D_) + h * HD_;
    const __bf16* kgl   = qbase + D_;
    const __bf16* vgl   = vt + (size_t)(b * H_ + h) * HD_ * N_;

    // ---- stage K [576x64] and V^T [64x576] into LDS (swizzled): 4608 chunks each
#pragma unroll 3
    for (int it = 0; it < 9; ++it) {
        int s = it * 512 + tid;
        int r = s >> 3, p = s & 7;                 // K: row, phys chunk
        int l = p ^ (r & 7);
        __builtin_amdgcn_global_load_lds(
            (const __attribute__((address_space(1))) void*)(kgl + (size_t)r * (2 * D_) + l * 8),
            (__attribute__((address_space(3))) void*)&Ks[(size_t)(it * 512 + wave * 64) * 8],
            16, 0, 0);
        int d = s / 72, pv = s - d * 72;           // V: row d, phys chunk
        int lv = (pv & ~7) | ((pv & 7) ^ (d & 7));
        __builtin_amdgcn_global_load_lds(
            (const __attribute__((address_space(1))) void*)(vgl + (size_t)d * N_ + lv * 8),
            (__attribute__((address_space(3))) void*)&Vs[(size_t)(it * 512 + wave * 64) * 8],
            16, 0, 0);
    }
    __syncthreads();

    // per-h scalars
    const float g   = 1.f / (1.f + __expf(-gating[h]));
    const float omg = 1.f - g;
    const float w0 = W_pos[h] * LOG2E, w1 = W_pos[H_ + h] * LOG2E,
                w2 = W_pos[2 * H_ + h] * LOG2E;
    const float kk = 0.125f * LOG2E;               // scale*log2(e)

    // per-lane column constants (fully unrolled -> registers)
    float fc[36], uu[36], vv[36];
#pragma unroll
    for (int ct = 0; ct < 36; ++ct) {
        int c = ct * 16 + fr;
        float cx = (float)(c % 24), cy = (float)(c / 24);
        fc[ct] = fmaf(w2, fmaf(cx, cx, cy * cy), fmaf(w0, cx, w1 * cy));
        uu[ct] = -2.f * w2 * cx;
        vv[ct] = -2.f * w2 * cy;
    }

    __bf16* sw = &Sc[wave * 16 * 48];

    for (int tt = wave; tt < 36; tt += 8) {
        const int n0 = tt * 16;

        // Q A-frags (global, read-once)
        const __bf16* qp = qbase + (size_t)(n0 + fr) * (2 * D_) + quad * 8;
        bf16x8 qf0 = *(const bf16x8*)qp;
        bf16x8 qf1 = *(const bf16x8*)(qp + 32);

        // ---- S = Q @ K^T (K from LDS); S in registers ----
        f32x4 S[36];
#pragma unroll
        for (int ct = 0; ct < 36; ++ct) {
            int row = ct * 16 + fr;
            int p0 = quad ^ (row & 7);
            int p1 = (4 + quad) ^ (row & 7);
            bf16x8 k0 = *(const bf16x8*)&Ks[row * 64 + p0 * 8];
            bf16x8 k1 = *(const bf16x8*)&Ks[row * 64 + p1 * 8];
            f32x4 a = (f32x4){0.f, 0.f, 0.f, 0.f};
            a = __builtin_amdgcn_mfma_f32_16x16x32_bf16(qf0, k0, a, 0, 0, 0);
            a = __builtin_amdgcn_mfma_f32_16x16x32_bf16(qf1, k1, a, 0, 0, 0);
            S[ct] = a;
        }

        // ---- per-row constants ----
        float frx[4], fry[4], Cpt[4];
#pragma unroll
        for (int t = 0; t < 4; ++t) {
            int n = n0 + quad * 4 + t;
            float rx = (float)(n % 24), ry = (float)(n / 24);
            frx[t] = rx; fry[t] = ry;
            float gr = fmaf(w2, fmaf(rx, rx, ry * ry), -fmaf(w0, rx, w1 * ry));
            Cpt[t] = Cp[h * N_ + n] + gr;
        }

        // ---- softmax (content part) ----
        float inv[4];
#pragma unroll
        for (int t = 0; t < 4; ++t) {
            float m = -1e30f;
#pragma unroll
            for (int ct = 0; ct < 36; ++ct) m = fmaxf(m, S[ct][t]);
            m = fmaxf(m, __shfl_xor(m, 1, 16));
            m = fmaxf(m, __shfl_xor(m, 2, 16));
            m = fmaxf(m, __shfl_xor(m, 4, 16));
            m = fmaxf(m, __shfl_xor(m, 8, 16));
            float km = kk * m;
            float s = 0.f;
#pragma unroll
            for (int ct = 0; ct < 36; ++ct) {
                float e = __builtin_amdgcn_exp2f(fmaf(kk, S[ct][t], -km));
                S[ct][t] = e;
                s += e;
            }
            s += __shfl_xor(s, 1, 16);
            s += __shfl_xor(s, 2, 16);
            s += __shfl_xor(s, 4, 16);
            s += __shfl_xor(s, 8, 16);
            inv[t] = omg / s;
        }

        // ---- PV: per 32-col chunk, mix P into LDS then MFMA ----
        f32x4 O[4];
#pragma unroll
        for (int dt = 0; dt < 4; ++dt) O[dt] = (f32x4){0.f, 0.f, 0.f, 0.f};
#pragma unroll
        for (int kb = 0; kb < 18; ++kb) {
#pragma unroll
            for (int ctl = 0; ctl < 2; ++ctl) {
                int ct = 2 * kb + ctl;
#pragma unroll
                for (int t = 0; t < 4; ++t) {
                    float pl = fmaf(frx[t], uu[ct], fc[ct]);
                    pl = fmaf(fry[t], vv[ct], pl) + Cpt[t];
                    float pval = fmaf(S[ct][t], inv[t], __builtin_amdgcn_exp2f(pl));
                    sw[(quad * 4 + t) * 48 + ctl * 16 + fr] = (__bf16)pval;
                }
            }
            bf16x8 pf = *(const bf16x8*)&sw[fr * 48 + quad * 8];
#pragma unroll
            for (int dt = 0; dt < 4; ++dt) {
                int d = dt * 16 + fr;
                int l = kb * 4 + quad;
                int p = (l & ~7) | ((l & 7) ^ (d & 7));
                bf16x8 vf = *(const bf16x8*)&Vs[d * 576 + p * 8];
                O[dt] = __builtin_amdgcn_mfma_f32_16x16x32_bf16(vf, pf, O[dt], 0, 0, 0);
            }
        }

        // ---- repack O via scratch, two 32-col passes, coalesced 16B stores ----
        asm volatile("s_waitcnt lgkmcnt(0)" ::: "memory");  // WAR: P reads done
#pragma unroll
        for (int ps = 0; ps < 2; ++ps) {
#pragma unroll
            for (int dh = 0; dh < 2; ++dh) {
                int dt = 2 * ps + dh;
                bf16x4 o4;
#pragma unroll
                for (int t = 0; t < 4; ++t) o4[t] = (__bf16)O[dt][t];
                // lane holds O^T[d=dt*16+quad*4+t][n=fr] -> store [n=fr][d-local]
                *(bf16x4*)&sw[fr * 48 + dh * 16 + quad * 4] = o4;
            }
            asm volatile("s_waitcnt lgkmcnt(0)" ::: "memory");
            {
                int row = lane >> 2;            // n row 0..15
                int off = (lane & 3) * 8;       // d-local offset 0..24
                bf16x8 ov = *(const bf16x8*)&sw[row * 48 + off];
                *(bf16x8*)&ao[((size_t)b * N_ + n0 + row) * D_ + h * HD_ + ps * 32 + off] = ov;
            }
            asm volatile("s_waitcnt lgkmcnt(0)" ::: "memory");  // reads done before next write
        }
    }
}

// ---------------------------------------------------------------------------
extern "C" void kernel_launch(void* const* d_in, const int* in_sizes, int n_in,
                              void* d_out, int out_size, void* d_ws, size_t ws_size,
                              hipStream_t stream)
{
    const float* x      = (const float*)d_in[0];
    const float* W_qk   = (const float*)d_in[1];
    const float* W_v    = (const float*)d_in[2];
    const float* W_proj = (const float*)d_in[3];
    const float* b_proj = (const float*)d_in[4];
    const float* W_pos  = (const float*)d_in[5];
    const float* b_pos  = (const float*)d_in[6];   // unused: cancels in softmax
    const float* gating = (const float*)d_in[7];
    const float* rel    = (const float*)d_in[8];   // unused: computed on the fly
    (void)b_pos; (void)rel;
    float* out = (float*)d_out;

    // workspace carve (~105 MB)
    char* p = (char*)d_ws;
    __bf16* xb    = (__bf16*)p;  p += (size_t)BN_ * D_ * 2;            // 18.9 MB
    __bf16* wqkvt = (__bf16*)p;  p += (size_t)(3 * D_) * D_ * 2;       //  6.3 MB
    __bf16* wpt   = (__bf16*)p;  p += (size_t)D_ * D_ * 2;             //  2.1 MB
    __bf16* qkb   = (__bf16*)p;  p += (size_t)BN_ * (2 * D_) * 2;      // 37.7 MB
    __bf16* vt    = (__bf16*)p;  p += (size_t)BN_ * D_ * 2;            // 18.9 MB [b,h,d,m]
    __bf16* aob   = (__bf16*)p;  p += (size_t)BN_ * D_ * 2;            // 18.9 MB
    float*  Cp    = (float*)p;                                         // 36 KB

    cast_bf16<<<(BN_ * D_) / 1024, 256, 0, stream>>>(x, xb);
    // concat [W_qk | W_v]^T into wqkvt[3072][1024]
    transpose_cast<<<dim3((2 * D_) / 64, D_ / 64), 256, 0, stream>>>(W_qk, wqkvt, D_, 2 * D_);
    transpose_cast<<<dim3(D_ / 64, D_ / 64), 256, 0, stream>>>(W_v, wqkvt + (size_t)2 * D_ * D_, D_, D_);
    transpose_cast<<<dim3(D_ / 64, D_ / 64), 256, 0, stream>>>(W_proj, wpt, D_, D_);

    // fused qk|v GEMM: N=3072; cols<2048 -> qkb, cols>=2048 -> vt (transposed)
    gemm_mfma<3><<<dim3((3 * D_) / 128, BN_ / 128), 256, 0, stream>>>(
        xb, wqkvt, nullptr, qkb, vt, BN_, 3 * D_, D_);
    pos_stats<<<H_ * N_, 64, 0, stream>>>(W_pos, gating, Cp);
    attn_mfma3<<<B_ * H_, 512, 0, stream>>>(qkb, vt, Cp, W_pos, gating, aob);
    gemm_mfma<0><<<dim3(D_ / 128, BN_ / 128), 256, 0, stream>>>(
        aob, wpt, b_proj, out, nullptr, BN_, D_, D_);
}